// Round 1
// baseline (2630.466 us; speedup 1.0000x reference)
//
#include <hip/hip_runtime.h>
#include <stdint.h>

// Problem dims
#define TOK 2048   // B*S
#define DD  1024   // D
#define RH  4096   // router hidden H
#define HE  4096   // expert hidden
#define NE  8      // experts
#define CH  2048   // combiner hidden 2D

using bf16x8 = __attribute__((ext_vector_type(8))) short;
using f32x4  = __attribute__((ext_vector_type(4))) float;

__device__ __forceinline__ unsigned short f2bf(float f) {
  union { float f; uint32_t u; } v; v.f = f;
  uint32_t r = (v.u + 0x7fffu + ((v.u >> 16) & 1u)) >> 16;
  return (unsigned short)r;
}
__device__ __forceinline__ float bf2f(unsigned short h) {
  union { uint32_t u; float f; } v; v.u = ((uint32_t)h) << 16;
  return v.f;
}
__device__ __forceinline__ float gelu_f(float x) {
  return 0.5f * x * (1.0f + erff(x * 0.70710678118654752440f));
}

// async global->LDS, 16B per lane; LDS dest = wave-uniform base + lane*16
#define GLD(SRC, DST) __builtin_amdgcn_global_load_lds( \
    (const __attribute__((address_space(1))) uint32_t*)(const void*)(SRC), \
    (__attribute__((address_space(3))) uint32_t*)(void*)(DST), 16, 0, 0)

// block (256 threads) LN stats over 1024 values (4 per thread already summed)
__device__ __forceinline__ void block_ln_stats(float s1, float s2, float& mean, float& rstd) {
  #pragma unroll
  for (int off = 32; off > 0; off >>= 1) {
    s1 += __shfl_down(s1, off);
    s2 += __shfl_down(s2, off);
  }
  __shared__ float sh[8];
  int tid = threadIdx.x;
  if ((tid & 63) == 0) { sh[tid >> 6] = s1; sh[4 + (tid >> 6)] = s2; }
  __syncthreads();
  float t1 = sh[0] + sh[1] + sh[2] + sh[3];
  float t2 = sh[4] + sh[5] + sh[6] + sh[7];
  mean = t1 * (1.0f / 1024.0f);
  float var = t2 * (1.0f / 1024.0f) - mean * mean;
  rstd = rsqrtf(var + 1e-5f);
}

// ---- h = x + pos_encoding; shared LN stats; xhat fp32 + bf16 hi/lo ----
__global__ void k_prep(const float* __restrict__ x, float* __restrict__ h,
                       float* __restrict__ xh32, unsigned short* __restrict__ xhi,
                       unsigned short* __restrict__ xlo) {
  int t = blockIdx.x;
  int s = t & 1023;
  int tid = threadIdx.x;
  float4 xv = ((const float4*)(x + (size_t)t * DD))[tid];
  float v[4]; float s1 = 0.f, s2 = 0.f;
  #pragma unroll
  for (int k = 0; k < 4; ++k) {
    int d = tid * 4 + k;
    float xc = (k == 0) ? xv.x : (k == 1) ? xv.y : (k == 2) ? xv.z : xv.w;
    float i2 = (float)(d & ~1);
    float div = expf(-9.2103403719761836f * i2 * (1.0f / 1024.0f));
    float ang = (float)s * div;
    float pe = (d & 1) ? cosf(ang) : sinf(ang);
    float hv = xc + pe;
    v[k] = hv; s1 += hv; s2 += hv * hv;
  }
  float mean, rstd;
  block_ln_stats(s1, s2, mean, rstd);
  float4 ho; ho.x = v[0]; ho.y = v[1]; ho.z = v[2]; ho.w = v[3];
  ((float4*)(h + (size_t)t * DD))[tid] = ho;
  float xn[4]; unsigned short hh[4], ll[4];
  #pragma unroll
  for (int k = 0; k < 4; ++k) {
    xn[k] = (v[k] - mean) * rstd;
    hh[k] = f2bf(xn[k]);
    ll[k] = f2bf(xn[k] - bf2f(hh[k]));
  }
  float4 xo; xo.x = xn[0]; xo.y = xn[1]; xo.z = xn[2]; xo.w = xn[3];
  ((float4*)(xh32 + (size_t)t * DD))[tid] = xo;
  ushort4 h4; h4.x = hh[0]; h4.y = hh[1]; h4.z = hh[2]; h4.w = hh[3];
  ((ushort4*)(xhi + (size_t)t * DD))[tid] = h4;
  ushort4 l4; l4.x = ll[0]; l4.y = ll[1]; l4.z = ll[2]; l4.w = ll[3];
  ((ushort4*)(xlo + (size_t)t * DD))[tid] = l4;
}

// ---- transpose+convert weights: in fp32 [D,N] (opt row-scale g[D]) -> out bf16 [N,D] ----
__global__ void k_tconv(const float* __restrict__ in, const float* __restrict__ g,
                        unsigned short* __restrict__ out, int D, int N,
                        long long in_bs, long long g_bs, long long out_bs) {
  __shared__ float tile[32][33];
  int e = blockIdx.z;
  const float* inb = in + (size_t)e * in_bs;
  unsigned short* outb = out + (size_t)e * out_bs;
  int n0 = blockIdx.x * 32, d0 = blockIdx.y * 32;
  int tn = threadIdx.x & 31, tr = threadIdx.x >> 5;
  #pragma unroll
  for (int rr = 0; rr < 4; ++rr) {
    int dl = tr + rr * 8;
    float v = inb[(size_t)(d0 + dl) * N + n0 + tn];
    if (g) v *= g[(size_t)e * g_bs + d0 + dl];
    tile[dl][tn] = v;
  }
  __syncthreads();
  #pragma unroll
  for (int rr = 0; rr < 4; ++rr) {
    int nl = tr + rr * 8;
    outb[(size_t)(n0 + nl) * D + d0 + tn] = f2bf(tile[tn][nl]);
  }
}

// router variant: writes bf16 hi, bf16 lo, and fp32 transposed copies
__global__ void k_tconv_split(const float* __restrict__ in, const float* __restrict__ g,
                              unsigned short* __restrict__ oh, unsigned short* __restrict__ ol,
                              float* __restrict__ o32, int D, int N) {
  __shared__ float tile[32][33];
  int n0 = blockIdx.x * 32, d0 = blockIdx.y * 32;
  int tn = threadIdx.x & 31, tr = threadIdx.x >> 5;
  #pragma unroll
  for (int rr = 0; rr < 4; ++rr) {
    int dl = tr + rr * 8;
    float v = in[(size_t)(d0 + dl) * N + n0 + tn];
    if (g) v *= g[d0 + dl];
    tile[dl][tn] = v;
  }
  __syncthreads();
  #pragma unroll
  for (int rr = 0; rr < 4; ++rr) {
    int nl = tr + rr * 8;
    float v = tile[tn][nl];
    size_t off = (size_t)(n0 + nl) * D + d0 + tn;
    unsigned short hi = f2bf(v);
    oh[off] = hi;
    ol[off] = f2bf(v - bf2f(hi));
    o32[off] = v;
  }
}

// ---- bias fold: out[n] = b1[n] + sum_d lnb[d]*w[d,n]  (skips w reads if lnb[d]==0) ----
__global__ void k_foldbias(const float* __restrict__ w, const float* __restrict__ lnb,
                           const float* __restrict__ b1, float* __restrict__ outb,
                           int D, int N, long long w_bs, long long lnb_bs,
                           long long b_bs, long long o_bs) {
  int e = blockIdx.y;
  int n = blockIdx.x * 256 + threadIdx.x;
  const float* wb = w + (size_t)e * w_bs;
  const float* lb = lnb + (size_t)e * lnb_bs;
  float acc = b1[(size_t)e * b_bs + n];
  for (int d = 0; d < D; ++d) {
    float l = lb[d];
    if (l != 0.f) acc += l * wb[(size_t)d * N + n];
  }
  outb[(size_t)e * o_bs + n] = acc;
}

// ---- main bf16 GEMM: C[M,N] = A[M,K] @ Bt[N,K]^T (+bias[col], opt gelu) ----
// 128x128 tile, BK=32, 4 waves (2x2 of 64x64), 16x16x32 MFMA, global_load_lds staging
template <int DO_GELU, int OUT_BF16>
__global__ __launch_bounds__(256)
void k_gemm(const unsigned short* __restrict__ A, const unsigned short* __restrict__ B,
            const float* __restrict__ bias, void* __restrict__ Cv, int N, int K,
            long long a_bs, long long b_bs, long long bias_bs, long long c_bs) {
  __shared__ __align__(16) unsigned short As[128 * 32];
  __shared__ __align__(16) unsigned short Bs[128 * 32];
  const int tid = threadIdx.x;
  const int w = tid >> 6, lane = tid & 63;
  const int q = lane >> 4, r16 = lane & 15;
  const int e = blockIdx.z;
  const int n0 = blockIdx.x * 128, m0 = blockIdx.y * 128;
  const unsigned short* Ab = A + (size_t)e * a_bs;
  const unsigned short* Bb = B + (size_t)e * b_bs;
  f32x4 acc[4][4];
  #pragma unroll
  for (int i = 0; i < 4; ++i)
    #pragma unroll
    for (int j = 0; j < 4; ++j) acc[i][j] = (f32x4){0.f, 0.f, 0.f, 0.f};
  const int srow = w * 32 + (lane >> 2);
  const int scol = (lane & 3) * 8;
  const unsigned short* a_src = Ab + (size_t)(m0 + srow) * K + scol;
  const unsigned short* b_src = Bb + (size_t)(n0 + srow) * K + scol;
  unsigned short* a_dst = &As[w * 1024];
  unsigned short* b_dst = &Bs[w * 1024];
  const int wm = w >> 1, wn = w & 1;
  for (int kt = 0; kt < K; kt += 32) {
    GLD(a_src + kt, a_dst);
    GLD(a_src + kt + (size_t)16 * K, a_dst + 512);
    GLD(b_src + kt, b_dst);
    GLD(b_src + kt + (size_t)16 * K, b_dst + 512);
    __syncthreads();
    bf16x8 af[4], bfv[4];
    #pragma unroll
    for (int i = 0; i < 4; ++i)
      af[i] = *(const bf16x8*)&As[(wm * 64 + i * 16 + r16) * 32 + q * 8];
    #pragma unroll
    for (int j = 0; j < 4; ++j)
      bfv[j] = *(const bf16x8*)&Bs[(wn * 64 + j * 16 + r16) * 32 + q * 8];
    #pragma unroll
    for (int i = 0; i < 4; ++i)
      #pragma unroll
      for (int j = 0; j < 4; ++j)
        acc[i][j] = __builtin_amdgcn_mfma_f32_16x16x32_bf16(af[i], bfv[j], acc[i][j], 0, 0, 0);
    __syncthreads();
  }
  #pragma unroll
  for (int j = 0; j < 4; ++j) {
    int col = n0 + wn * 64 + j * 16 + r16;
    float bv = bias[(size_t)e * bias_bs + col];
    #pragma unroll
    for (int i = 0; i < 4; ++i) {
      int row = m0 + wm * 64 + i * 16 + q * 4;
      #pragma unroll
      for (int t2 = 0; t2 < 4; ++t2) {
        float vv = acc[i][j][t2] + bv;
        if (DO_GELU) vv = gelu_f(vv);
        size_t off = (size_t)e * c_bs + (size_t)(row + t2) * N + col;
        if (OUT_BF16) ((unsigned short*)Cv)[off] = f2bf(vv);
        else ((float*)Cv)[off] = vv;
      }
    }
  }
}

// ---- split-precision router GEMM1: (Ah+Al) @ (Bh+Bl)^T, 3 MFMA per tile, gelu, fp32 out ----
__global__ __launch_bounds__(256)
void k_gemm_split(const unsigned short* __restrict__ Ah, const unsigned short* __restrict__ Al,
                  const unsigned short* __restrict__ Bh, const unsigned short* __restrict__ Bl,
                  const float* __restrict__ bias, float* __restrict__ C, int N, int K) {
  __shared__ __align__(16) unsigned short Ahs[128 * 32];
  __shared__ __align__(16) unsigned short Als[128 * 32];
  __shared__ __align__(16) unsigned short Bhs[128 * 32];
  __shared__ __align__(16) unsigned short Bls[128 * 32];
  const int tid = threadIdx.x;
  const int w = tid >> 6, lane = tid & 63;
  const int q = lane >> 4, r16 = lane & 15;
  const int n0 = blockIdx.x * 128, m0 = blockIdx.y * 128;
  f32x4 acc[4][4];
  #pragma unroll
  for (int i = 0; i < 4; ++i)
    #pragma unroll
    for (int j = 0; j < 4; ++j) acc[i][j] = (f32x4){0.f, 0.f, 0.f, 0.f};
  const int srow = w * 32 + (lane >> 2);
  const int scol = (lane & 3) * 8;
  const unsigned short* ah_src = Ah + (size_t)(m0 + srow) * K + scol;
  const unsigned short* al_src = Al + (size_t)(m0 + srow) * K + scol;
  const unsigned short* bh_src = Bh + (size_t)(n0 + srow) * K + scol;
  const unsigned short* bl_src = Bl + (size_t)(n0 + srow) * K + scol;
  const int wm = w >> 1, wn = w & 1;
  for (int kt = 0; kt < K; kt += 32) {
    GLD(ah_src + kt, &Ahs[w * 1024]);
    GLD(ah_src + kt + (size_t)16 * K, &Ahs[w * 1024 + 512]);
    GLD(al_src + kt, &Als[w * 1024]);
    GLD(al_src + kt + (size_t)16 * K, &Als[w * 1024 + 512]);
    GLD(bh_src + kt, &Bhs[w * 1024]);
    GLD(bh_src + kt + (size_t)16 * K, &Bhs[w * 1024 + 512]);
    GLD(bl_src + kt, &Bls[w * 1024]);
    GLD(bl_src + kt + (size_t)16 * K, &Bls[w * 1024 + 512]);
    __syncthreads();
    bf16x8 ah[4], al[4], bh[4], bl[4];
    #pragma unroll
    for (int i = 0; i < 4; ++i) {
      int o = (wm * 64 + i * 16 + r16) * 32 + q * 8;
      ah[i] = *(const bf16x8*)&Ahs[o];
      al[i] = *(const bf16x8*)&Als[o];
    }
    #pragma unroll
    for (int j = 0; j < 4; ++j) {
      int o = (wn * 64 + j * 16 + r16) * 32 + q * 8;
      bh[j] = *(const bf16x8*)&Bhs[o];
      bl[j] = *(const bf16x8*)&Bls[o];
    }
    #pragma unroll
    for (int i = 0; i < 4; ++i)
      #pragma unroll
      for (int j = 0; j < 4; ++j) {
        acc[i][j] = __builtin_amdgcn_mfma_f32_16x16x32_bf16(ah[i], bh[j], acc[i][j], 0, 0, 0);
        acc[i][j] = __builtin_amdgcn_mfma_f32_16x16x32_bf16(al[i], bh[j], acc[i][j], 0, 0, 0);
        acc[i][j] = __builtin_amdgcn_mfma_f32_16x16x32_bf16(ah[i], bl[j], acc[i][j], 0, 0, 0);
      }
    __syncthreads();
  }
  #pragma unroll
  for (int j = 0; j < 4; ++j) {
    int col = n0 + wn * 64 + j * 16 + r16;
    float bv = bias[col];
    #pragma unroll
    for (int i = 0; i < 4; ++i) {
      int row = m0 + wm * 64 + i * 16 + q * 4;
      #pragma unroll
      for (int t2 = 0; t2 < 4; ++t2)
        C[(size_t)(row + t2) * N + col] = gelu_f(acc[i][j][t2] + bv);
    }
  }
}

// ---- router GEMM2 + softmax + top2 -> gate; flag near-tie tokens ----
__global__ void k_logits(const float* __restrict__ r, const float* __restrict__ w2,
                         const float* __restrict__ b2, const float* __restrict__ temp,
                         float* __restrict__ gate, int* __restrict__ flag) {
  int t = blockIdx.x, tid = threadIdx.x;
  const float* rr = r + (size_t)t * RH;
  float acc[NE];
  #pragma unroll
  for (int e = 0; e < NE; ++e) acc[e] = 0.f;
  #pragma unroll
  for (int k4 = 0; k4 < 4; ++k4) {
    float4 rv4 = ((const float4*)rr)[tid * 4 + k4];
    #pragma unroll
    for (int kk = 0; kk < 4; ++kk) {
      int d = tid * 16 + k4 * 4 + kk;
      float rv = (kk == 0) ? rv4.x : (kk == 1) ? rv4.y : (kk == 2) ? rv4.z : rv4.w;
      const float4* wr = (const float4*)(w2 + (size_t)d * NE);
      float4 w0 = wr[0], w1 = wr[1];
      acc[0] += rv * w0.x; acc[1] += rv * w0.y; acc[2] += rv * w0.z; acc[3] += rv * w0.w;
      acc[4] += rv * w1.x; acc[5] += rv * w1.y; acc[6] += rv * w1.z; acc[7] += rv * w1.w;
    }
  }
  #pragma unroll
  for (int off = 32; off > 0; off >>= 1)
    #pragma unroll
    for (int e = 0; e < NE; ++e) acc[e] += __shfl_down(acc[e], off);
  __shared__ float shl[4][NE];
  int w = tid >> 6, lane = tid & 63;
  if (lane == 0) {
    #pragma unroll
    for (int e = 0; e < NE; ++e) shl[w][e] = acc[e];
  }
  __syncthreads();
  if (tid == 0) {
    float tmp = temp[0];
    float lg[NE];
    #pragma unroll
    for (int e = 0; e < NE; ++e)
      lg[e] = (shl[0][e] + shl[1][e] + shl[2][e] + shl[3][e] + b2[e]) / tmp;
    float mx = lg[0];
    for (int e = 1; e < NE; ++e) mx = fmaxf(mx, lg[e]);
    float p[NE], se = 0.f;
    for (int e = 0; e < NE; ++e) { p[e] = expf(lg[e] - mx); se += p[e]; }
    float inv = 1.f / se;
    int i1 = 0; float p1 = p[0];
    for (int e = 1; e < NE; ++e) if (p[e] > p1) { p1 = p[e]; i1 = e; }
    int i2 = -1; float p2 = -1.f;
    for (int e = 0; e < NE; ++e) if (e != i1 && p[e] > p2) { p2 = p[e]; i2 = e; }
    for (int e = 0; e < NE; ++e) gate[(size_t)t * NE + e] = 0.f;
    gate[(size_t)t * NE + i1] = p1 * inv;
    gate[(size_t)t * NE + i2] = p2 * inv;
    // flag if 2nd/3rd logit gap is within split-precision noise margin
    float a1 = -1e30f, a2 = -1e30f, a3 = -1e30f;
    for (int e = 0; e < NE; ++e) {
      float vv = lg[e];
      if (vv > a1) { a3 = a2; a2 = a1; a1 = vv; }
      else if (vv > a2) { a3 = a2; a2 = vv; }
      else if (vv > a3) a3 = vv;
    }
    flag[t] = (a2 - a3 < 0.01f) ? 1 : 0;
  }
}

// ---- exact fp32 recompute of gate for flagged (near-tie) tokens ----
__global__ void k_triage(const int* __restrict__ flag, const float* __restrict__ xh32,
                         const float* __restrict__ W32, const float* __restrict__ biasr,
                         const float* __restrict__ w2, const float* __restrict__ b2,
                         const float* __restrict__ temp, float* __restrict__ gate) {
  int t = blockIdx.x;
  if (flag[t] == 0) return;
  int tid = threadIdx.x;
  int w = tid >> 6, lane = tid & 63;
  __shared__ float xs[DD];
  ((float4*)xs)[tid] = ((const float4*)(xh32 + (size_t)t * DD))[tid];
  __syncthreads();
  float acc[NE];
  #pragma unroll
  for (int e = 0; e < NE; ++e) acc[e] = 0.f;
  for (int hh = w; hh < RH; hh += 4) {
    const float4* wrow = (const float4*)(W32 + (size_t)hh * DD);
    float s = 0.f;
    #pragma unroll
    for (int c = 0; c < 4; ++c) {
      float4 wv = wrow[lane + 64 * c];
      float4 xv = ((const float4*)xs)[lane + 64 * c];
      s += wv.x * xv.x + wv.y * xv.y + wv.z * xv.z + wv.w * xv.w;
    }
    #pragma unroll
    for (int off = 32; off > 0; off >>= 1) s += __shfl_down(s, off);
    if (lane == 0) {
      float r1 = gelu_f(s + biasr[hh]);
      const float* wr = w2 + (size_t)hh * NE;
      #pragma unroll
      for (int e = 0; e < NE; ++e) acc[e] += r1 * wr[e];
    }
  }
  __shared__ float sh2[4][NE];
  if (lane == 0) {
    #pragma unroll
    for (int e = 0; e < NE; ++e) sh2[w][e] = acc[e];
  }
  __syncthreads();
  if (tid == 0) {
    float tmp = temp[0];
    float lg[NE];
    #pragma unroll
    for (int e = 0; e < NE; ++e)
      lg[e] = (sh2[0][e] + sh2[1][e] + sh2[2][e] + sh2[3][e] + b2[e]) / tmp;
    float mx = lg[0];
    for (int e = 1; e < NE; ++e) mx = fmaxf(mx, lg[e]);
    float p[NE], se = 0.f;
    for (int e = 0; e < NE; ++e) { p[e] = expf(lg[e] - mx); se += p[e]; }
    float inv = 1.f / se;
    int i1 = 0; float p1 = p[0];
    for (int e = 1; e < NE; ++e) if (p[e] > p1) { p1 = p[e]; i1 = e; }
    int i2 = -1; float p2 = -1.f;
    for (int e = 0; e < NE; ++e) if (e != i1 && p[e] > p2) { p2 = p[e]; i2 = e; }
    for (int e = 0; e < NE; ++e) gate[(size_t)t * NE + e] = 0.f;
    gate[(size_t)t * NE + i1] = p1 * inv;
    gate[(size_t)t * NE + i2] = p2 * inv;
  }
}

// ---- combined = sum_e gate*f2 ; LN -> xc (normalized, gamma/beta folded into Wc1/bc1) ----
__global__ void k_combine(const float* __restrict__ gate, const unsigned short* __restrict__ f2,
                          unsigned short* __restrict__ xc) {
  int t = blockIdx.x, tid = threadIdx.x;
  __shared__ float g8[NE];
  if (tid < NE) g8[tid] = gate[(size_t)t * NE + tid];
  __syncthreads();
  float v[4] = {0.f, 0.f, 0.f, 0.f};
  for (int e = 0; e < NE; ++e) {
    float g = g8[e];
    if (g != 0.f) {
      ushort4 u = ((const ushort4*)(f2 + ((size_t)e * TOK + t) * DD))[tid];
      v[0] += g * bf2f(u.x); v[1] += g * bf2f(u.y);
      v[2] += g * bf2f(u.z); v[3] += g * bf2f(u.w);
    }
  }
  float s1 = v[0] + v[1] + v[2] + v[3];
  float s2 = v[0]*v[0] + v[1]*v[1] + v[2]*v[2] + v[3]*v[3];
  float mean, rstd;
  block_ln_stats(s1, s2, mean, rstd);
  ushort4 o;
  o.x = f2bf((v[0] - mean) * rstd); o.y = f2bf((v[1] - mean) * rstd);
  o.z = f2bf((v[2] - mean) * rstd); o.w = f2bf((v[3] - mean) * rstd);
  ((ushort4*)(xc + (size_t)t * DD))[tid] = o;
}

// ---- out = layernorm(h + c2, o_g, o_b) ----
__global__ void k_final(const float* __restrict__ h, const unsigned short* __restrict__ c2,
                        const float* __restrict__ og, const float* __restrict__ ob,
                        float* __restrict__ out) {
  int t = blockIdx.x, tid = threadIdx.x;
  float4 hv = ((const float4*)(h + (size_t)t * DD))[tid];
  ushort4 cu = ((const ushort4*)(c2 + (size_t)t * DD))[tid];
  float v[4] = {hv.x + bf2f(cu.x), hv.y + bf2f(cu.y), hv.z + bf2f(cu.z), hv.w + bf2f(cu.w)};
  float s1 = v[0] + v[1] + v[2] + v[3];
  float s2 = v[0]*v[0] + v[1]*v[1] + v[2]*v[2] + v[3]*v[3];
  float mean, rstd;
  block_ln_stats(s1, s2, mean, rstd);
  float4 gv = ((const float4*)og)[tid];
  float4 bv = ((const float4*)ob)[tid];
  float4 o;
  o.x = (v[0] - mean) * rstd * gv.x + bv.x;
  o.y = (v[1] - mean) * rstd * gv.y + bv.y;
  o.z = (v[2] - mean) * rstd * gv.z + bv.z;
  o.w = (v[3] - mean) * rstd * gv.w + bv.w;
  ((float4*)(out + (size_t)t * DD))[tid] = o;
}

extern "C" void kernel_launch(void* const* d_in, const int* in_sizes, int n_in,
                              void* d_out, int out_size, void* d_ws, size_t ws_size,
                              hipStream_t stream) {
  (void)in_sizes; (void)n_in; (void)out_size;
  const float* x      = (const float*)d_in[0];
  const float* r_ln_g = (const float*)d_in[1];
  const float* r_ln_b = (const float*)d_in[2];
  const float* r_w1   = (const float*)d_in[3];
  const float* r_b1   = (const float*)d_in[4];
  const float* r_w2   = (const float*)d_in[5];
  const float* r_b2   = (const float*)d_in[6];
  const float* temp   = (const float*)d_in[7];
  const float* e_ln_g = (const float*)d_in[8];
  const float* e_ln_b = (const float*)d_in[9];
  const float* e_w1   = (const float*)d_in[10];
  const float* e_b1   = (const float*)d_in[11];
  const float* e_w2   = (const float*)d_in[12];
  const float* e_b2   = (const float*)d_in[13];
  const float* c_ln_g = (const float*)d_in[14];
  const float* c_ln_b = (const float*)d_in[15];
  const float* c_w1   = (const float*)d_in[16];
  const float* c_b1   = (const float*)d_in[17];
  const float* c_w2   = (const float*)d_in[18];
  const float* c_b2   = (const float*)d_in[19];
  const float* o_ln_g = (const float*)d_in[20];
  const float* o_ln_b = (const float*)d_in[21];
  float* out = (float*)d_out;

  char* base = (char*)d_ws;
  long long cur = 0;
  auto take = [&](long long sz) { char* r = base + cur; cur += (sz + 255) & ~255LL; return r; };

  float* h      = (float*)take(8388608);            // [2048,1024] fp32
  float* xh32   = (float*)take(8388608);            // xhat fp32
  unsigned short* xhi = (unsigned short*)take(4194304); // xhat bf16 hi
  unsigned short* xlo = (unsigned short*)take(4194304); // xhat bf16 lo
  unsigned short* WrH = (unsigned short*)take(8388608); // router W1^T*g hi
  unsigned short* WrL = (unsigned short*)take(8388608);
  float* Wr32   = (float*)take(16777216);           // router W1^T*g fp32 (triage)
  float* biasr  = (float*)take(16384);
  float* ract   = (float*)take(33554432);           // gelu(router GEMM1) fp32
  float* gate   = (float*)take(65536);
  int*   flag   = (int*)take(8192);
  unsigned short* We1 = (unsigned short*)take(67108864); // [8][4096,1024]
  float* be1    = (float*)take(131072);
  unsigned short* We2 = (unsigned short*)take(67108864); // [8][1024,4096]
  unsigned short* f2  = (unsigned short*)take(33554432); // [8][2048,1024] bf16
  unsigned short* Wc1 = (unsigned short*)take(4194304);
  float* bc1    = (float*)take(8192);
  unsigned short* Wc2 = (unsigned short*)take(4194304);
  unsigned short* xc  = (unsigned short*)take(4194304);
  unsigned short* c1  = (unsigned short*)take(8388608);
  unsigned short* c2  = (unsigned short*)take(4194304);
  long long remain = (long long)ws_size - cur;
  bool full = remain >= 134217728LL;  // F1 dense over all experts vs 1 expert at a time
  unsigned short* F1 = (unsigned short*)take(full ? 134217728LL : 16777216LL);

  // prep + weight conversion
  k_prep<<<TOK, 256, 0, stream>>>(x, h, xh32, xhi, xlo);
  k_tconv_split<<<dim3(RH/32, DD/32, 1), 256, 0, stream>>>(r_w1, r_ln_g, WrH, WrL, Wr32, DD, RH);
  k_tconv<<<dim3(RH/32, DD/32, NE), 256, 0, stream>>>(e_w1, e_ln_g, We1, DD, RH,
      (long long)DD*RH, (long long)DD, (long long)RH*DD);
  k_tconv<<<dim3(DD/32, HE/32, NE), 256, 0, stream>>>(e_w2, nullptr, We2, HE, DD,
      (long long)HE*DD, 0LL, (long long)DD*HE);
  k_tconv<<<dim3(CH/32, DD/32, 1), 256, 0, stream>>>(c_w1, c_ln_g, Wc1, DD, CH, 0LL, 0LL, 0LL);
  k_tconv<<<dim3(DD/32, CH/32, 1), 256, 0, stream>>>(c_w2, nullptr, Wc2, CH, DD, 0LL, 0LL, 0LL);
  k_foldbias<<<dim3(RH/256, 1), 256, 0, stream>>>(r_w1, r_ln_b, r_b1, biasr, DD, RH, 0LL, 0LL, 0LL, 0LL);
  k_foldbias<<<dim3(RH/256, NE), 256, 0, stream>>>(e_w1, e_ln_b, e_b1, be1, DD, RH,
      (long long)DD*RH, (long long)DD, (long long)RH, (long long)RH);
  k_foldbias<<<dim3(CH/256, 1), 256, 0, stream>>>(c_w1, c_ln_b, c_b1, bc1, DD, CH, 0LL, 0LL, 0LL, 0LL);

  // router (split precision) + gate + near-tie triage
  k_gemm_split<<<dim3(RH/128, TOK/128, 1), 256, 0, stream>>>(xhi, xlo, WrH, WrL, biasr, ract, RH, DD);
  k_logits<<<TOK, 256, 0, stream>>>(ract, r_w2, r_b2, temp, gate, flag);
  k_triage<<<TOK, 256, 0, stream>>>(flag, xh32, Wr32, biasr, r_w2, r_b2, temp, gate);

  // experts (dense)
  if (full) {
    k_gemm<1,1><<<dim3(RH/128, TOK/128, NE), 256, 0, stream>>>(xhi, We1, be1, (void*)F1, RH, DD,
        0LL, (long long)RH*DD, (long long)RH, (long long)TOK*RH);
    k_gemm<0,1><<<dim3(DD/128, TOK/128, NE), 256, 0, stream>>>(F1, We2, e_b2, (void*)f2, DD, HE,
        (long long)TOK*HE, (long long)DD*HE, (long long)DD, (long long)TOK*DD);
  } else {
    for (int e = 0; e < NE; ++e) {
      k_gemm<1,1><<<dim3(RH/128, TOK/128, 1), 256, 0, stream>>>(xhi, We1 + (long long)e*RH*DD,
          be1 + (long long)e*RH, (void*)F1, RH, DD, 0LL, 0LL, 0LL, 0LL);
      k_gemm<0,1><<<dim3(DD/128, TOK/128, 1), 256, 0, stream>>>(F1, We2 + (long long)e*DD*HE,
          e_b2 + (long long)e*DD, (void*)(f2 + (long long)e*TOK*DD), DD, HE, 0LL, 0LL, 0LL, 0LL);
    }
  }

  // combine + combiner MLP + residual/output LN
  k_combine<<<TOK, 256, 0, stream>>>(gate, f2, xc);
  k_gemm<1,1><<<dim3(CH/128, TOK/128, 1), 256, 0, stream>>>(xc, Wc1, bc1, (void*)c1, CH, DD, 0LL, 0LL, 0LL, 0LL);
  k_gemm<0,1><<<dim3(DD/128, TOK/128, 1), 256, 0, stream>>>(c1, Wc2, c_b2, (void*)c2, DD, CH, 0LL, 0LL, 0LL, 0LL);
  k_final<<<TOK, 256, 0, stream>>>(h, c2, o_ln_g, o_ln_b, out);
}

// Round 2
// 1354.137 us; speedup vs baseline: 1.9425x; 1.9425x over previous
//
#include <hip/hip_runtime.h>
#include <stdint.h>

// Problem dims
#define TOK 2048   // B*S
#define DD  1024   // D
#define RH  4096   // router hidden H
#define HE  4096   // expert hidden
#define NE  8      // experts
#define CH  2048   // combiner hidden 2D

using bf16x8 = __attribute__((ext_vector_type(8))) short;
using f32x4  = __attribute__((ext_vector_type(4))) float;

__device__ __forceinline__ unsigned short f2bf(float f) {
  union { float f; uint32_t u; } v; v.f = f;
  uint32_t r = (v.u + 0x7fffu + ((v.u >> 16) & 1u)) >> 16;
  return (unsigned short)r;
}
__device__ __forceinline__ float bf2f(unsigned short h) {
  union { uint32_t u; float f; } v; v.u = ((uint32_t)h) << 16;
  return v.f;
}
__device__ __forceinline__ float gelu_f(float x) {
  return 0.5f * x * (1.0f + erff(x * 0.70710678118654752440f));
}

// async global->LDS, 16B per lane; LDS dest = wave-uniform base + lane*16
#define GLD(SRC, DST) __builtin_amdgcn_global_load_lds( \
    (const __attribute__((address_space(1))) uint32_t*)(const void*)(SRC), \
    (__attribute__((address_space(3))) uint32_t*)(void*)(DST), 16, 0, 0)

// block (256 threads) LN stats over 1024 values (4 per thread already summed)
__device__ __forceinline__ void block_ln_stats(float s1, float s2, float& mean, float& rstd) {
  #pragma unroll
  for (int off = 32; off > 0; off >>= 1) {
    s1 += __shfl_down(s1, off);
    s2 += __shfl_down(s2, off);
  }
  __shared__ float sh[8];
  int tid = threadIdx.x;
  if ((tid & 63) == 0) { sh[tid >> 6] = s1; sh[4 + (tid >> 6)] = s2; }
  __syncthreads();
  float t1 = sh[0] + sh[1] + sh[2] + sh[3];
  float t2 = sh[4] + sh[5] + sh[6] + sh[7];
  mean = t1 * (1.0f / 1024.0f);
  float var = t2 * (1.0f / 1024.0f) - mean * mean;
  rstd = rsqrtf(var + 1e-5f);
}

// ---- h = x + pos_encoding; shared LN stats; xhat fp32 + bf16 hi/lo ----
__global__ void k_prep(const float* __restrict__ x, float* __restrict__ h,
                       float* __restrict__ xh32, unsigned short* __restrict__ xhi,
                       unsigned short* __restrict__ xlo) {
  int t = blockIdx.x;
  int s = t & 1023;
  int tid = threadIdx.x;
  float4 xv = ((const float4*)(x + (size_t)t * DD))[tid];
  float v[4]; float s1 = 0.f, s2 = 0.f;
  #pragma unroll
  for (int k = 0; k < 4; ++k) {
    int d = tid * 4 + k;
    float xc = (k == 0) ? xv.x : (k == 1) ? xv.y : (k == 2) ? xv.z : xv.w;
    float i2 = (float)(d & ~1);
    float div = expf(-9.2103403719761836f * i2 * (1.0f / 1024.0f));
    float ang = (float)s * div;
    float pe = (d & 1) ? cosf(ang) : sinf(ang);
    float hv = xc + pe;
    v[k] = hv; s1 += hv; s2 += hv * hv;
  }
  float mean, rstd;
  block_ln_stats(s1, s2, mean, rstd);
  float4 ho; ho.x = v[0]; ho.y = v[1]; ho.z = v[2]; ho.w = v[3];
  ((float4*)(h + (size_t)t * DD))[tid] = ho;
  float xn[4]; unsigned short hh[4], ll[4];
  #pragma unroll
  for (int k = 0; k < 4; ++k) {
    xn[k] = (v[k] - mean) * rstd;
    hh[k] = f2bf(xn[k]);
    ll[k] = f2bf(xn[k] - bf2f(hh[k]));
  }
  float4 xo; xo.x = xn[0]; xo.y = xn[1]; xo.z = xn[2]; xo.w = xn[3];
  ((float4*)(xh32 + (size_t)t * DD))[tid] = xo;
  ushort4 h4; h4.x = hh[0]; h4.y = hh[1]; h4.z = hh[2]; h4.w = hh[3];
  ((ushort4*)(xhi + (size_t)t * DD))[tid] = h4;
  ushort4 l4; l4.x = ll[0]; l4.y = ll[1]; l4.z = ll[2]; l4.w = ll[3];
  ((ushort4*)(xlo + (size_t)t * DD))[tid] = l4;
}

// ---- transpose+convert weights: in fp32 [D,N] (opt row-scale g[D]) -> out bf16 [N,D] ----
__global__ void k_tconv(const float* __restrict__ in, const float* __restrict__ g,
                        unsigned short* __restrict__ out, int D, int N,
                        long long in_bs, long long g_bs, long long out_bs) {
  __shared__ float tile[32][33];
  int e = blockIdx.z;
  const float* inb = in + (size_t)e * in_bs;
  unsigned short* outb = out + (size_t)e * out_bs;
  int n0 = blockIdx.x * 32, d0 = blockIdx.y * 32;
  int tn = threadIdx.x & 31, tr = threadIdx.x >> 5;
  #pragma unroll
  for (int rr = 0; rr < 4; ++rr) {
    int dl = tr + rr * 8;
    float v = inb[(size_t)(d0 + dl) * N + n0 + tn];
    if (g) v *= g[(size_t)e * g_bs + d0 + dl];
    tile[dl][tn] = v;
  }
  __syncthreads();
  #pragma unroll
  for (int rr = 0; rr < 4; ++rr) {
    int nl = tr + rr * 8;
    outb[(size_t)(n0 + nl) * D + d0 + tn] = f2bf(tile[tn][nl]);
  }
}

// router variant: writes bf16 hi, bf16 lo, and fp32 transposed copies
__global__ void k_tconv_split(const float* __restrict__ in, const float* __restrict__ g,
                              unsigned short* __restrict__ oh, unsigned short* __restrict__ ol,
                              float* __restrict__ o32, int D, int N) {
  __shared__ float tile[32][33];
  int n0 = blockIdx.x * 32, d0 = blockIdx.y * 32;
  int tn = threadIdx.x & 31, tr = threadIdx.x >> 5;
  #pragma unroll
  for (int rr = 0; rr < 4; ++rr) {
    int dl = tr + rr * 8;
    float v = in[(size_t)(d0 + dl) * N + n0 + tn];
    if (g) v *= g[d0 + dl];
    tile[dl][tn] = v;
  }
  __syncthreads();
  #pragma unroll
  for (int rr = 0; rr < 4; ++rr) {
    int nl = tr + rr * 8;
    float v = tile[tn][nl];
    size_t off = (size_t)(n0 + nl) * D + d0 + tn;
    unsigned short hi = f2bf(v);
    oh[off] = hi;
    ol[off] = f2bf(v - bf2f(hi));
    o32[off] = v;
  }
}

// ---- bias fold: out[n] = b1[n] + sum_d lnb[d]*w[d,n]  (skips w reads if lnb[d]==0) ----
__global__ void k_foldbias(const float* __restrict__ w, const float* __restrict__ lnb,
                           const float* __restrict__ b1, float* __restrict__ outb,
                           int D, int N, long long w_bs, long long lnb_bs,
                           long long b_bs, long long o_bs) {
  int e = blockIdx.y;
  int n = blockIdx.x * 256 + threadIdx.x;
  const float* wb = w + (size_t)e * w_bs;
  const float* lb = lnb + (size_t)e * lnb_bs;
  float acc = b1[(size_t)e * b_bs + n];
  for (int d = 0; d < D; ++d) {
    float l = lb[d];
    if (l != 0.f) acc += l * wb[(size_t)d * N + n];
  }
  outb[(size_t)e * o_bs + n] = acc;
}

// ---- main bf16 GEMM: C[M,N] = A[M,K] @ Bt[N,K]^T (+bias[col], opt gelu) ----
// 128x128 tile, BK=32, 4 waves (2x2 of 64x64), 16x16x32 MFMA, global_load_lds staging
template <int DO_GELU, int OUT_BF16>
__global__ __launch_bounds__(256)
void k_gemm(const unsigned short* __restrict__ A, const unsigned short* __restrict__ B,
            const float* __restrict__ bias, void* __restrict__ Cv, int N, int K,
            long long a_bs, long long b_bs, long long bias_bs, long long c_bs) {
  __shared__ __align__(16) unsigned short As[128 * 32];
  __shared__ __align__(16) unsigned short Bs[128 * 32];
  const int tid = threadIdx.x;
  const int w = tid >> 6, lane = tid & 63;
  const int q = lane >> 4, r16 = lane & 15;
  const int e = blockIdx.z;
  const int n0 = blockIdx.x * 128, m0 = blockIdx.y * 128;
  const unsigned short* Ab = A + (size_t)e * a_bs;
  const unsigned short* Bb = B + (size_t)e * b_bs;
  f32x4 acc[4][4];
  #pragma unroll
  for (int i = 0; i < 4; ++i)
    #pragma unroll
    for (int j = 0; j < 4; ++j) acc[i][j] = (f32x4){0.f, 0.f, 0.f, 0.f};
  const int srow = w * 32 + (lane >> 2);
  const int scol = (lane & 3) * 8;
  const unsigned short* a_src = Ab + (size_t)(m0 + srow) * K + scol;
  const unsigned short* b_src = Bb + (size_t)(n0 + srow) * K + scol;
  unsigned short* a_dst = &As[w * 1024];
  unsigned short* b_dst = &Bs[w * 1024];
  const int wm = w >> 1, wn = w & 1;
  for (int kt = 0; kt < K; kt += 32) {
    GLD(a_src + kt, a_dst);
    GLD(a_src + kt + (size_t)16 * K, a_dst + 512);
    GLD(b_src + kt, b_dst);
    GLD(b_src + kt + (size_t)16 * K, b_dst + 512);
    __syncthreads();
    bf16x8 af[4], bfv[4];
    #pragma unroll
    for (int i = 0; i < 4; ++i)
      af[i] = *(const bf16x8*)&As[(wm * 64 + i * 16 + r16) * 32 + q * 8];
    #pragma unroll
    for (int j = 0; j < 4; ++j)
      bfv[j] = *(const bf16x8*)&Bs[(wn * 64 + j * 16 + r16) * 32 + q * 8];
    #pragma unroll
    for (int i = 0; i < 4; ++i)
      #pragma unroll
      for (int j = 0; j < 4; ++j)
        acc[i][j] = __builtin_amdgcn_mfma_f32_16x16x32_bf16(af[i], bfv[j], acc[i][j], 0, 0, 0);
    __syncthreads();
  }
  #pragma unroll
  for (int j = 0; j < 4; ++j) {
    int col = n0 + wn * 64 + j * 16 + r16;
    float bv = bias[(size_t)e * bias_bs + col];
    #pragma unroll
    for (int i = 0; i < 4; ++i) {
      int row = m0 + wm * 64 + i * 16 + q * 4;
      #pragma unroll
      for (int t2 = 0; t2 < 4; ++t2) {
        float vv = acc[i][j][t2] + bv;
        if (DO_GELU) vv = gelu_f(vv);
        size_t off = (size_t)e * c_bs + (size_t)(row + t2) * N + col;
        if (OUT_BF16) ((unsigned short*)Cv)[off] = f2bf(vv);
        else ((float*)Cv)[off] = vv;
      }
    }
  }
}

// ---- split-precision router GEMM1: (Ah+Al) @ (Bh+Bl)^T, 3 MFMA per tile, gelu, fp32 out ----
__global__ __launch_bounds__(256)
void k_gemm_split(const unsigned short* __restrict__ Ah, const unsigned short* __restrict__ Al,
                  const unsigned short* __restrict__ Bh, const unsigned short* __restrict__ Bl,
                  const float* __restrict__ bias, float* __restrict__ C, int N, int K) {
  __shared__ __align__(16) unsigned short Ahs[128 * 32];
  __shared__ __align__(16) unsigned short Als[128 * 32];
  __shared__ __align__(16) unsigned short Bhs[128 * 32];
  __shared__ __align__(16) unsigned short Bls[128 * 32];
  const int tid = threadIdx.x;
  const int w = tid >> 6, lane = tid & 63;
  const int q = lane >> 4, r16 = lane & 15;
  const int n0 = blockIdx.x * 128, m0 = blockIdx.y * 128;
  f32x4 acc[4][4];
  #pragma unroll
  for (int i = 0; i < 4; ++i)
    #pragma unroll
    for (int j = 0; j < 4; ++j) acc[i][j] = (f32x4){0.f, 0.f, 0.f, 0.f};
  const int srow = w * 32 + (lane >> 2);
  const int scol = (lane & 3) * 8;
  const unsigned short* ah_src = Ah + (size_t)(m0 + srow) * K + scol;
  const unsigned short* al_src = Al + (size_t)(m0 + srow) * K + scol;
  const unsigned short* bh_src = Bh + (size_t)(n0 + srow) * K + scol;
  const unsigned short* bl_src = Bl + (size_t)(n0 + srow) * K + scol;
  const int wm = w >> 1, wn = w & 1;
  for (int kt = 0; kt < K; kt += 32) {
    GLD(ah_src + kt, &Ahs[w * 1024]);
    GLD(ah_src + kt + (size_t)16 * K, &Ahs[w * 1024 + 512]);
    GLD(al_src + kt, &Als[w * 1024]);
    GLD(al_src + kt + (size_t)16 * K, &Als[w * 1024 + 512]);
    GLD(bh_src + kt, &Bhs[w * 1024]);
    GLD(bh_src + kt + (size_t)16 * K, &Bhs[w * 1024 + 512]);
    GLD(bl_src + kt, &Bls[w * 1024]);
    GLD(bl_src + kt + (size_t)16 * K, &Bls[w * 1024 + 512]);
    __syncthreads();
    bf16x8 ah[4], al[4], bh[4], bl[4];
    #pragma unroll
    for (int i = 0; i < 4; ++i) {
      int o = (wm * 64 + i * 16 + r16) * 32 + q * 8;
      ah[i] = *(const bf16x8*)&Ahs[o];
      al[i] = *(const bf16x8*)&Als[o];
    }
    #pragma unroll
    for (int j = 0; j < 4; ++j) {
      int o = (wn * 64 + j * 16 + r16) * 32 + q * 8;
      bh[j] = *(const bf16x8*)&Bhs[o];
      bl[j] = *(const bf16x8*)&Bls[o];
    }
    #pragma unroll
    for (int i = 0; i < 4; ++i)
      #pragma unroll
      for (int j = 0; j < 4; ++j) {
        acc[i][j] = __builtin_amdgcn_mfma_f32_16x16x32_bf16(ah[i], bh[j], acc[i][j], 0, 0, 0);
        acc[i][j] = __builtin_amdgcn_mfma_f32_16x16x32_bf16(al[i], bh[j], acc[i][j], 0, 0, 0);
        acc[i][j] = __builtin_amdgcn_mfma_f32_16x16x32_bf16(ah[i], bl[j], acc[i][j], 0, 0, 0);
      }
    __syncthreads();
  }
  #pragma unroll
  for (int j = 0; j < 4; ++j) {
    int col = n0 + wn * 64 + j * 16 + r16;
    float bv = bias[col];
    #pragma unroll
    for (int i = 0; i < 4; ++i) {
      int row = m0 + wm * 64 + i * 16 + q * 4;
      #pragma unroll
      for (int t2 = 0; t2 < 4; ++t2)
        C[(size_t)(row + t2) * N + col] = gelu_f(acc[i][j][t2] + bv);
    }
  }
}

// ---- router GEMM2 + softmax + top2 -> gate; flag near-tie tokens (+zero their logit slot) ----
__global__ void k_logits(const float* __restrict__ r, const float* __restrict__ w2,
                         const float* __restrict__ b2, const float* __restrict__ temp,
                         float* __restrict__ gate, int* __restrict__ flag,
                         float* __restrict__ lg32) {
  int t = blockIdx.x, tid = threadIdx.x;
  const float* rr = r + (size_t)t * RH;
  float acc[NE];
  #pragma unroll
  for (int e = 0; e < NE; ++e) acc[e] = 0.f;
  #pragma unroll
  for (int k4 = 0; k4 < 4; ++k4) {
    float4 rv4 = ((const float4*)rr)[tid * 4 + k4];
    #pragma unroll
    for (int kk = 0; kk < 4; ++kk) {
      int d = tid * 16 + k4 * 4 + kk;
      float rv = (kk == 0) ? rv4.x : (kk == 1) ? rv4.y : (kk == 2) ? rv4.z : rv4.w;
      const float4* wr = (const float4*)(w2 + (size_t)d * NE);
      float4 w0 = wr[0], w1 = wr[1];
      acc[0] += rv * w0.x; acc[1] += rv * w0.y; acc[2] += rv * w0.z; acc[3] += rv * w0.w;
      acc[4] += rv * w1.x; acc[5] += rv * w1.y; acc[6] += rv * w1.z; acc[7] += rv * w1.w;
    }
  }
  #pragma unroll
  for (int off = 32; off > 0; off >>= 1)
    #pragma unroll
    for (int e = 0; e < NE; ++e) acc[e] += __shfl_down(acc[e], off);
  __shared__ float shl[4][NE];
  int w = tid >> 6, lane = tid & 63;
  if (lane == 0) {
    #pragma unroll
    for (int e = 0; e < NE; ++e) shl[w][e] = acc[e];
  }
  __syncthreads();
  if (tid == 0) {
    float tmp = temp[0];
    float lg[NE];
    #pragma unroll
    for (int e = 0; e < NE; ++e)
      lg[e] = (shl[0][e] + shl[1][e] + shl[2][e] + shl[3][e] + b2[e]) / tmp;
    float mx = lg[0];
    for (int e = 1; e < NE; ++e) mx = fmaxf(mx, lg[e]);
    float p[NE], se = 0.f;
    for (int e = 0; e < NE; ++e) { p[e] = expf(lg[e] - mx); se += p[e]; }
    float inv = 1.f / se;
    int i1 = 0; float p1 = p[0];
    for (int e = 1; e < NE; ++e) if (p[e] > p1) { p1 = p[e]; i1 = e; }
    int i2 = -1; float p2 = -1.f;
    for (int e = 0; e < NE; ++e) if (e != i1 && p[e] > p2) { p2 = p[e]; i2 = e; }
    for (int e = 0; e < NE; ++e) gate[(size_t)t * NE + e] = 0.f;
    gate[(size_t)t * NE + i1] = p1 * inv;
    gate[(size_t)t * NE + i2] = p2 * inv;
    // flag if 2nd/3rd logit gap is within split-precision noise margin
    float a1 = -1e30f, a2 = -1e30f, a3 = -1e30f;
    for (int e = 0; e < NE; ++e) {
      float vv = lg[e];
      if (vv > a1) { a3 = a2; a2 = a1; a1 = vv; }
      else if (vv > a2) { a3 = a2; a2 = vv; }
      else if (vv > a3) a3 = vv;
    }
    int fl = (a2 - a3 < 0.01f) ? 1 : 0;
    flag[t] = fl;
    if (fl) {
      #pragma unroll
      for (int e = 0; e < NE; ++e) lg32[(size_t)t * NE + e] = 0.f;
    }
  }
}

// ---- parallel exact fp32 recompute of raw logits (GEMM2 sums) for flagged tokens ----
// grid (RH/64, TOK): each active block handles 64 rows of RH (16/wave), atomicAdds 8 partials
__global__ void k_triage2(const int* __restrict__ flag, const float* __restrict__ xh32,
                          const float* __restrict__ W32, const float* __restrict__ biasr,
                          const float* __restrict__ w2, float* __restrict__ lg32) {
  int t = blockIdx.y;
  if (flag[t] == 0) return;
  int tid = threadIdx.x;
  int w = tid >> 6, lane = tid & 63;
  __shared__ float xs[DD];
  ((float4*)xs)[tid] = ((const float4*)(xh32 + (size_t)t * DD))[tid];
  __syncthreads();
  int hh0 = blockIdx.x * 64 + w * 16;
  float acc[NE];
  #pragma unroll
  for (int e = 0; e < NE; ++e) acc[e] = 0.f;
  #pragma unroll
  for (int r = 0; r < 16; ++r) {
    int hh = hh0 + r;
    const float4* wrow = (const float4*)(W32 + (size_t)hh * DD);
    float s = 0.f;
    #pragma unroll
    for (int c = 0; c < 4; ++c) {
      float4 wv = wrow[lane + 64 * c];
      float4 xv = ((const float4*)xs)[lane + 64 * c];
      s += wv.x * xv.x + wv.y * xv.y + wv.z * xv.z + wv.w * xv.w;
    }
    #pragma unroll
    for (int off = 32; off > 0; off >>= 1) s += __shfl_down(s, off);
    if (lane == 0) {
      float r1 = gelu_f(s + biasr[hh]);
      const float* wr = w2 + (size_t)hh * NE;
      #pragma unroll
      for (int e = 0; e < NE; ++e) acc[e] += r1 * wr[e];
    }
  }
  __shared__ float sh2[4][NE];
  if (lane == 0) {
    #pragma unroll
    for (int e = 0; e < NE; ++e) sh2[w][e] = acc[e];
  }
  __syncthreads();
  if (tid < NE) {
    float v = sh2[0][tid] + sh2[1][tid] + sh2[2][tid] + sh2[3][tid];
    atomicAdd(&lg32[(size_t)t * NE + tid], v);
  }
}

// ---- finalize gate for flagged tokens from exact logits ----
__global__ void k_gate2(const int* __restrict__ flag, const float* __restrict__ lg32,
                        const float* __restrict__ b2, const float* __restrict__ temp,
                        float* __restrict__ gate) {
  int t = blockIdx.x * 256 + threadIdx.x;
  if (t >= TOK || flag[t] == 0) return;
  float tmp = temp[0];
  float lg[NE];
  #pragma unroll
  for (int e = 0; e < NE; ++e) lg[e] = (lg32[(size_t)t * NE + e] + b2[e]) / tmp;
  float mx = lg[0];
  for (int e = 1; e < NE; ++e) mx = fmaxf(mx, lg[e]);
  float p[NE], se = 0.f;
  for (int e = 0; e < NE; ++e) { p[e] = expf(lg[e] - mx); se += p[e]; }
  float inv = 1.f / se;
  int i1 = 0; float p1 = p[0];
  for (int e = 1; e < NE; ++e) if (p[e] > p1) { p1 = p[e]; i1 = e; }
  int i2 = -1; float p2 = -1.f;
  for (int e = 0; e < NE; ++e) if (e != i1 && p[e] > p2) { p2 = p[e]; i2 = e; }
  for (int e = 0; e < NE; ++e) gate[(size_t)t * NE + e] = 0.f;
  gate[(size_t)t * NE + i1] = p1 * inv;
  gate[(size_t)t * NE + i2] = p2 * inv;
}

// ---- combined = sum_e gate*f2 ; LN -> xc (normalized, gamma/beta folded into Wc1/bc1) ----
__global__ void k_combine(const float* __restrict__ gate, const unsigned short* __restrict__ f2,
                          unsigned short* __restrict__ xc) {
  int t = blockIdx.x, tid = threadIdx.x;
  __shared__ float g8[NE];
  if (tid < NE) g8[tid] = gate[(size_t)t * NE + tid];
  __syncthreads();
  float v[4] = {0.f, 0.f, 0.f, 0.f};
  for (int e = 0; e < NE; ++e) {
    float g = g8[e];
    if (g != 0.f) {
      ushort4 u = ((const ushort4*)(f2 + ((size_t)e * TOK + t) * DD))[tid];
      v[0] += g * bf2f(u.x); v[1] += g * bf2f(u.y);
      v[2] += g * bf2f(u.z); v[3] += g * bf2f(u.w);
    }
  }
  float s1 = v[0] + v[1] + v[2] + v[3];
  float s2 = v[0]*v[0] + v[1]*v[1] + v[2]*v[2] + v[3]*v[3];
  float mean, rstd;
  block_ln_stats(s1, s2, mean, rstd);
  ushort4 o;
  o.x = f2bf((v[0] - mean) * rstd); o.y = f2bf((v[1] - mean) * rstd);
  o.z = f2bf((v[2] - mean) * rstd); o.w = f2bf((v[3] - mean) * rstd);
  ((ushort4*)(xc + (size_t)t * DD))[tid] = o;
}

// ---- out = layernorm(h + c2, o_g, o_b) ----
__global__ void k_final(const float* __restrict__ h, const unsigned short* __restrict__ c2,
                        const float* __restrict__ og, const float* __restrict__ ob,
                        float* __restrict__ out) {
  int t = blockIdx.x, tid = threadIdx.x;
  float4 hv = ((const float4*)(h + (size_t)t * DD))[tid];
  ushort4 cu = ((const ushort4*)(c2 + (size_t)t * DD))[tid];
  float v[4] = {hv.x + bf2f(cu.x), hv.y + bf2f(cu.y), hv.z + bf2f(cu.z), hv.w + bf2f(cu.w)};
  float s1 = v[0] + v[1] + v[2] + v[3];
  float s2 = v[0]*v[0] + v[1]*v[1] + v[2]*v[2] + v[3]*v[3];
  float mean, rstd;
  block_ln_stats(s1, s2, mean, rstd);
  float4 gv = ((const float4*)og)[tid];
  float4 bv = ((const float4*)ob)[tid];
  float4 o;
  o.x = (v[0] - mean) * rstd * gv.x + bv.x;
  o.y = (v[1] - mean) * rstd * gv.y + bv.y;
  o.z = (v[2] - mean) * rstd * gv.z + bv.z;
  o.w = (v[3] - mean) * rstd * gv.w + bv.w;
  ((float4*)(out + (size_t)t * DD))[tid] = o;
}

extern "C" void kernel_launch(void* const* d_in, const int* in_sizes, int n_in,
                              void* d_out, int out_size, void* d_ws, size_t ws_size,
                              hipStream_t stream) {
  (void)in_sizes; (void)n_in; (void)out_size;
  const float* x      = (const float*)d_in[0];
  const float* r_ln_g = (const float*)d_in[1];
  const float* r_ln_b = (const float*)d_in[2];
  const float* r_w1   = (const float*)d_in[3];
  const float* r_b1   = (const float*)d_in[4];
  const float* r_w2   = (const float*)d_in[5];
  const float* r_b2   = (const float*)d_in[6];
  const float* temp   = (const float*)d_in[7];
  const float* e_ln_g = (const float*)d_in[8];
  const float* e_ln_b = (const float*)d_in[9];
  const float* e_w1   = (const float*)d_in[10];
  const float* e_b1   = (const float*)d_in[11];
  const float* e_w2   = (const float*)d_in[12];
  const float* e_b2   = (const float*)d_in[13];
  const float* c_ln_g = (const float*)d_in[14];
  const float* c_ln_b = (const float*)d_in[15];
  const float* c_w1   = (const float*)d_in[16];
  const float* c_b1   = (const float*)d_in[17];
  const float* c_w2   = (const float*)d_in[18];
  const float* c_b2   = (const float*)d_in[19];
  const float* o_ln_g = (const float*)d_in[20];
  const float* o_ln_b = (const float*)d_in[21];
  float* out = (float*)d_out;

  char* base = (char*)d_ws;
  long long cur = 0;
  auto take = [&](long long sz) { char* r = base + cur; cur += (sz + 255) & ~255LL; return r; };

  float* h      = (float*)take(8388608);            // [2048,1024] fp32
  float* xh32   = (float*)take(8388608);            // xhat fp32
  unsigned short* xhi = (unsigned short*)take(4194304); // xhat bf16 hi
  unsigned short* xlo = (unsigned short*)take(4194304); // xhat bf16 lo
  unsigned short* WrH = (unsigned short*)take(8388608); // router W1^T*g hi
  unsigned short* WrL = (unsigned short*)take(8388608);
  float* Wr32   = (float*)take(16777216);           // router W1^T*g fp32 (triage)
  float* biasr  = (float*)take(16384);
  float* ract   = (float*)take(33554432);           // gelu(router GEMM1) fp32
  float* gate   = (float*)take(65536);
  int*   flag   = (int*)take(8192);
  float* lg32   = (float*)take(65536);              // exact fp32 logits (triage accum)
  unsigned short* We1 = (unsigned short*)take(67108864); // [8][4096,1024]
  float* be1    = (float*)take(131072);
  unsigned short* We2 = (unsigned short*)take(67108864); // [8][1024,4096]
  unsigned short* f2  = (unsigned short*)take(33554432); // [8][2048,1024] bf16
  unsigned short* Wc1 = (unsigned short*)take(4194304);
  float* bc1    = (float*)take(8192);
  unsigned short* Wc2 = (unsigned short*)take(4194304);
  unsigned short* xc  = (unsigned short*)take(4194304);
  unsigned short* c1  = (unsigned short*)take(8388608);
  unsigned short* c2  = (unsigned short*)take(4194304);
  long long remain = (long long)ws_size - cur;
  bool full = remain >= 134217728LL;  // F1 dense over all experts vs 1 expert at a time
  unsigned short* F1 = (unsigned short*)take(full ? 134217728LL : 16777216LL);

  // prep + weight conversion
  k_prep<<<TOK, 256, 0, stream>>>(x, h, xh32, xhi, xlo);
  k_tconv_split<<<dim3(RH/32, DD/32, 1), 256, 0, stream>>>(r_w1, r_ln_g, WrH, WrL, Wr32, DD, RH);
  k_tconv<<<dim3(RH/32, DD/32, NE), 256, 0, stream>>>(e_w1, e_ln_g, We1, DD, RH,
      (long long)DD*RH, (long long)DD, (long long)RH*DD);
  k_tconv<<<dim3(DD/32, HE/32, NE), 256, 0, stream>>>(e_w2, nullptr, We2, HE, DD,
      (long long)HE*DD, 0LL, (long long)DD*HE);
  k_tconv<<<dim3(CH/32, DD/32, 1), 256, 0, stream>>>(c_w1, c_ln_g, Wc1, DD, CH, 0LL, 0LL, 0LL);
  k_tconv<<<dim3(DD/32, CH/32, 1), 256, 0, stream>>>(c_w2, nullptr, Wc2, CH, DD, 0LL, 0LL, 0LL);
  k_foldbias<<<dim3(RH/256, 1), 256, 0, stream>>>(r_w1, r_ln_b, r_b1, biasr, DD, RH, 0LL, 0LL, 0LL, 0LL);
  k_foldbias<<<dim3(RH/256, NE), 256, 0, stream>>>(e_w1, e_ln_b, e_b1, be1, DD, RH,
      (long long)DD*RH, (long long)DD, (long long)RH, (long long)RH);
  k_foldbias<<<dim3(CH/256, 1), 256, 0, stream>>>(c_w1, c_ln_b, c_b1, bc1, DD, CH, 0LL, 0LL, 0LL, 0LL);

  // router (split precision) + gate + near-tie parallel triage
  k_gemm_split<<<dim3(RH/128, TOK/128, 1), 256, 0, stream>>>(xhi, xlo, WrH, WrL, biasr, ract, RH, DD);
  k_logits<<<TOK, 256, 0, stream>>>(ract, r_w2, r_b2, temp, gate, flag, lg32);
  k_triage2<<<dim3(RH/64, TOK), 256, 0, stream>>>(flag, xh32, Wr32, biasr, r_w2, lg32);
  k_gate2<<<TOK/256, 256, 0, stream>>>(flag, lg32, r_b2, temp, gate);

  // experts (dense)
  if (full) {
    k_gemm<1,1><<<dim3(RH/128, TOK/128, NE), 256, 0, stream>>>(xhi, We1, be1, (void*)F1, RH, DD,
        0LL, (long long)RH*DD, (long long)RH, (long long)TOK*RH);
    k_gemm<0,1><<<dim3(DD/128, TOK/128, NE), 256, 0, stream>>>(F1, We2, e_b2, (void*)f2, DD, HE,
        (long long)TOK*HE, (long long)DD*HE, (long long)DD, (long long)TOK*DD);
  } else {
    for (int e = 0; e < NE; ++e) {
      k_gemm<1,1><<<dim3(RH/128, TOK/128, 1), 256, 0, stream>>>(xhi, We1 + (long long)e*RH*DD,
          be1 + (long long)e*RH, (void*)F1, RH, DD, 0LL, 0LL, 0LL, 0LL);
      k_gemm<0,1><<<dim3(DD/128, TOK/128, 1), 256, 0, stream>>>(F1, We2 + (long long)e*DD*HE,
          e_b2 + (long long)e*DD, (void*)(f2 + (long long)e*TOK*DD), DD, HE, 0LL, 0LL, 0LL, 0LL);
    }
  }

  // combine + combiner MLP + residual/output LN
  k_combine<<<TOK, 256, 0, stream>>>(gate, f2, xc);
  k_gemm<1,1><<<dim3(CH/128, TOK/128, 1), 256, 0, stream>>>(xc, Wc1, bc1, (void*)c1, CH, DD, 0LL, 0LL, 0LL, 0LL);
  k_gemm<0,1><<<dim3(DD/128, TOK/128, 1), 256, 0, stream>>>(c1, Wc2, c_b2, (void*)c2, DD, CH, 0LL, 0LL, 0LL, 0LL);
  k_final<<<TOK, 256, 0, stream>>>(h, c2, o_ln_g, o_ln_b, out);
}

// Round 3
// 1092.494 us; speedup vs baseline: 2.4078x; 1.2395x over previous
//
#include <hip/hip_runtime.h>
#include <stdint.h>

// Problem dims
#define TOK 2048   // B*S
#define DD  1024   // D
#define RH  4096   // router hidden H
#define HE  4096   // expert hidden
#define NE  8      // experts
#define CH  2048   // combiner hidden 2D
#define MAXTILE 40    // max 128-row tiles across experts: 4096/128 + 7 = 39
#define MAXROWS 5120  // 4096 pairs + 8*127 pad, rounded up

using bf16x8 = __attribute__((ext_vector_type(8))) short;
using f32x4  = __attribute__((ext_vector_type(4))) float;

__device__ __forceinline__ unsigned short f2bf(float f) {
  union { float f; uint32_t u; } v; v.f = f;
  uint32_t r = (v.u + 0x7fffu + ((v.u >> 16) & 1u)) >> 16;
  return (unsigned short)r;
}
__device__ __forceinline__ float bf2f(unsigned short h) {
  union { uint32_t u; float f; } v; v.u = ((uint32_t)h) << 16;
  return v.f;
}
__device__ __forceinline__ float gelu_f(float x) {
  return 0.5f * x * (1.0f + erff(x * 0.70710678118654752440f));
}

// async global->LDS, 16B per lane; LDS dest = wave-uniform base + lane*16
#define GLD(SRC, DST) __builtin_amdgcn_global_load_lds( \
    (const __attribute__((address_space(1))) uint32_t*)(const void*)(SRC), \
    (__attribute__((address_space(3))) uint32_t*)(void*)(DST), 16, 0, 0)

// block (256 threads) LN stats over 1024 values (4 per thread already summed)
__device__ __forceinline__ void block_ln_stats(float s1, float s2, float& mean, float& rstd) {
  #pragma unroll
  for (int off = 32; off > 0; off >>= 1) {
    s1 += __shfl_down(s1, off);
    s2 += __shfl_down(s2, off);
  }
  __shared__ float sh[8];
  int tid = threadIdx.x;
  if ((tid & 63) == 0) { sh[tid >> 6] = s1; sh[4 + (tid >> 6)] = s2; }
  __syncthreads();
  float t1 = sh[0] + sh[1] + sh[2] + sh[3];
  float t2 = sh[4] + sh[5] + sh[6] + sh[7];
  mean = t1 * (1.0f / 1024.0f);
  float var = t2 * (1.0f / 1024.0f) - mean * mean;
  rstd = rsqrtf(var + 1e-5f);
}

// ---- h = x + pos_encoding; shared LN stats; xhat fp32 + bf16 hi/lo ----
__global__ void k_prep(const float* __restrict__ x, float* __restrict__ h,
                       float* __restrict__ xh32, unsigned short* __restrict__ xhi,
                       unsigned short* __restrict__ xlo) {
  int t = blockIdx.x;
  int s = t & 1023;
  int tid = threadIdx.x;
  float4 xv = ((const float4*)(x + (size_t)t * DD))[tid];
  float v[4]; float s1 = 0.f, s2 = 0.f;
  #pragma unroll
  for (int k = 0; k < 4; ++k) {
    int d = tid * 4 + k;
    float xc = (k == 0) ? xv.x : (k == 1) ? xv.y : (k == 2) ? xv.z : xv.w;
    float i2 = (float)(d & ~1);
    float div = expf(-9.2103403719761836f * i2 * (1.0f / 1024.0f));
    float ang = (float)s * div;
    float pe = (d & 1) ? cosf(ang) : sinf(ang);
    float hv = xc + pe;
    v[k] = hv; s1 += hv; s2 += hv * hv;
  }
  float mean, rstd;
  block_ln_stats(s1, s2, mean, rstd);
  float4 ho; ho.x = v[0]; ho.y = v[1]; ho.z = v[2]; ho.w = v[3];
  ((float4*)(h + (size_t)t * DD))[tid] = ho;
  float xn[4]; unsigned short hh[4], ll[4];
  #pragma unroll
  for (int k = 0; k < 4; ++k) {
    xn[k] = (v[k] - mean) * rstd;
    hh[k] = f2bf(xn[k]);
    ll[k] = f2bf(xn[k] - bf2f(hh[k]));
  }
  float4 xo; xo.x = xn[0]; xo.y = xn[1]; xo.z = xn[2]; xo.w = xn[3];
  ((float4*)(xh32 + (size_t)t * DD))[tid] = xo;
  ushort4 h4; h4.x = hh[0]; h4.y = hh[1]; h4.z = hh[2]; h4.w = hh[3];
  ((ushort4*)(xhi + (size_t)t * DD))[tid] = h4;
  ushort4 l4; l4.x = ll[0]; l4.y = ll[1]; l4.z = ll[2]; l4.w = ll[3];
  ((ushort4*)(xlo + (size_t)t * DD))[tid] = l4;
}

// ---- transpose+convert weights: in fp32 [D,N] (opt row-scale g[D]) -> out bf16 [N,D] ----
__global__ void k_tconv(const float* __restrict__ in, const float* __restrict__ g,
                        unsigned short* __restrict__ out, int D, int N,
                        long long in_bs, long long g_bs, long long out_bs) {
  __shared__ float tile[32][33];
  int e = blockIdx.z;
  const float* inb = in + (size_t)e * in_bs;
  unsigned short* outb = out + (size_t)e * out_bs;
  int n0 = blockIdx.x * 32, d0 = blockIdx.y * 32;
  int tn = threadIdx.x & 31, tr = threadIdx.x >> 5;
  #pragma unroll
  for (int rr = 0; rr < 4; ++rr) {
    int dl = tr + rr * 8;
    float v = inb[(size_t)(d0 + dl) * N + n0 + tn];
    if (g) v *= g[(size_t)e * g_bs + d0 + dl];
    tile[dl][tn] = v;
  }
  __syncthreads();
  #pragma unroll
  for (int rr = 0; rr < 4; ++rr) {
    int nl = tr + rr * 8;
    outb[(size_t)(n0 + nl) * D + d0 + tn] = f2bf(tile[tn][nl]);
  }
}

// router variant: writes bf16 hi, bf16 lo, and fp32 transposed copies
__global__ void k_tconv_split(const float* __restrict__ in, const float* __restrict__ g,
                              unsigned short* __restrict__ oh, unsigned short* __restrict__ ol,
                              float* __restrict__ o32, int D, int N) {
  __shared__ float tile[32][33];
  int n0 = blockIdx.x * 32, d0 = blockIdx.y * 32;
  int tn = threadIdx.x & 31, tr = threadIdx.x >> 5;
  #pragma unroll
  for (int rr = 0; rr < 4; ++rr) {
    int dl = tr + rr * 8;
    float v = in[(size_t)(d0 + dl) * N + n0 + tn];
    if (g) v *= g[d0 + dl];
    tile[dl][tn] = v;
  }
  __syncthreads();
  #pragma unroll
  for (int rr = 0; rr < 4; ++rr) {
    int nl = tr + rr * 8;
    float v = tile[tn][nl];
    size_t off = (size_t)(n0 + nl) * D + d0 + tn;
    unsigned short hi = f2bf(v);
    oh[off] = hi;
    ol[off] = f2bf(v - bf2f(hi));
    o32[off] = v;
  }
}

// ---- bias fold: out[n] = b1[n] + sum_d lnb[d]*w[d,n]  (skips w reads if lnb[d]==0) ----
__global__ void k_foldbias(const float* __restrict__ w, const float* __restrict__ lnb,
                           const float* __restrict__ b1, float* __restrict__ outb,
                           int D, int N, long long w_bs, long long lnb_bs,
                           long long b_bs, long long o_bs) {
  int e = blockIdx.y;
  int n = blockIdx.x * 256 + threadIdx.x;
  const float* wb = w + (size_t)e * w_bs;
  const float* lb = lnb + (size_t)e * lnb_bs;
  float acc = b1[(size_t)e * b_bs + n];
  for (int d = 0; d < D; ++d) {
    float l = lb[d];
    if (l != 0.f) acc += l * wb[(size_t)d * N + n];
  }
  outb[(size_t)e * o_bs + n] = acc;
}

// ---- main bf16 GEMM: C[M,N] = A[M,K] @ Bt[N,K]^T (+bias[col], opt gelu) ----
template <int DO_GELU, int OUT_BF16>
__global__ __launch_bounds__(256)
void k_gemm(const unsigned short* __restrict__ A, const unsigned short* __restrict__ B,
            const float* __restrict__ bias, void* __restrict__ Cv, int N, int K,
            long long a_bs, long long b_bs, long long bias_bs, long long c_bs) {
  __shared__ __align__(16) unsigned short As[128 * 32];
  __shared__ __align__(16) unsigned short Bs[128 * 32];
  const int tid = threadIdx.x;
  const int w = tid >> 6, lane = tid & 63;
  const int q = lane >> 4, r16 = lane & 15;
  const int e = blockIdx.z;
  const int n0 = blockIdx.x * 128, m0 = blockIdx.y * 128;
  const unsigned short* Ab = A + (size_t)e * a_bs;
  const unsigned short* Bb = B + (size_t)e * b_bs;
  f32x4 acc[4][4];
  #pragma unroll
  for (int i = 0; i < 4; ++i)
    #pragma unroll
    for (int j = 0; j < 4; ++j) acc[i][j] = (f32x4){0.f, 0.f, 0.f, 0.f};
  const int srow = w * 32 + (lane >> 2);
  const int scol = (lane & 3) * 8;
  const unsigned short* a_src = Ab + (size_t)(m0 + srow) * K + scol;
  const unsigned short* b_src = Bb + (size_t)(n0 + srow) * K + scol;
  unsigned short* a_dst = &As[w * 1024];
  unsigned short* b_dst = &Bs[w * 1024];
  const int wm = w >> 1, wn = w & 1;
  for (int kt = 0; kt < K; kt += 32) {
    GLD(a_src + kt, a_dst);
    GLD(a_src + kt + (size_t)16 * K, a_dst + 512);
    GLD(b_src + kt, b_dst);
    GLD(b_src + kt + (size_t)16 * K, b_dst + 512);
    __syncthreads();
    bf16x8 af[4], bfv[4];
    #pragma unroll
    for (int i = 0; i < 4; ++i)
      af[i] = *(const bf16x8*)&As[(wm * 64 + i * 16 + r16) * 32 + q * 8];
    #pragma unroll
    for (int j = 0; j < 4; ++j)
      bfv[j] = *(const bf16x8*)&Bs[(wn * 64 + j * 16 + r16) * 32 + q * 8];
    #pragma unroll
    for (int i = 0; i < 4; ++i)
      #pragma unroll
      for (int j = 0; j < 4; ++j)
        acc[i][j] = __builtin_amdgcn_mfma_f32_16x16x32_bf16(af[i], bfv[j], acc[i][j], 0, 0, 0);
    __syncthreads();
  }
  #pragma unroll
  for (int j = 0; j < 4; ++j) {
    int col = n0 + wn * 64 + j * 16 + r16;
    float bv = bias[(size_t)e * bias_bs + col];
    #pragma unroll
    for (int i = 0; i < 4; ++i) {
      int row = m0 + wm * 64 + i * 16 + q * 4;
      #pragma unroll
      for (int t2 = 0; t2 < 4; ++t2) {
        float vv = acc[i][j][t2] + bv;
        if (DO_GELU) vv = gelu_f(vv);
        size_t off = (size_t)e * c_bs + (size_t)(row + t2) * N + col;
        if (OUT_BF16) ((unsigned short*)Cv)[off] = f2bf(vv);
        else ((float*)Cv)[off] = vv;
      }
    }
  }
}

// ---- grouped expert GEMM1: gathered tokens -> gelu -> F1g [slot][RH] ----
__global__ __launch_bounds__(256)
void k_gemm_g1(const unsigned short* __restrict__ A, const unsigned short* __restrict__ W,
               const float* __restrict__ bias, unsigned short* __restrict__ C,
               const int* __restrict__ tok_of, const int* __restrict__ tile_e,
               const int* __restrict__ tile_r0, const int* __restrict__ ntiles) {
  if ((int)blockIdx.y >= *ntiles) return;
  __shared__ __align__(16) unsigned short As[128 * 32];
  __shared__ __align__(16) unsigned short Bs[128 * 32];
  const int tid = threadIdx.x;
  const int w = tid >> 6, lane = tid & 63;
  const int q = lane >> 4, r16 = lane & 15;
  const int e = tile_e[blockIdx.y];
  const int row0 = tile_r0[blockIdx.y];
  const int n0 = blockIdx.x * 128;
  f32x4 acc[4][4];
  #pragma unroll
  for (int i = 0; i < 4; ++i)
    #pragma unroll
    for (int j = 0; j < 4; ++j) acc[i][j] = (f32x4){0.f, 0.f, 0.f, 0.f};
  const int srow = w * 32 + (lane >> 2);
  const int scol = (lane & 3) * 8;
  const int t0 = tok_of[row0 + srow];
  const int t1 = tok_of[row0 + srow + 16];
  const unsigned short* a_src0 = A + (size_t)t0 * DD + scol;
  const unsigned short* a_src1 = A + (size_t)t1 * DD + scol;
  const unsigned short* b_src = W + (size_t)e * RH * DD + (size_t)(n0 + srow) * DD + scol;
  unsigned short* a_dst = &As[w * 1024];
  unsigned short* b_dst = &Bs[w * 1024];
  const int wm = w >> 1, wn = w & 1;
  for (int kt = 0; kt < DD; kt += 32) {
    GLD(a_src0 + kt, a_dst);
    GLD(a_src1 + kt, a_dst + 512);
    GLD(b_src + kt, b_dst);
    GLD(b_src + kt + (size_t)16 * DD, b_dst + 512);
    __syncthreads();
    bf16x8 af[4], bfv[4];
    #pragma unroll
    for (int i = 0; i < 4; ++i)
      af[i] = *(const bf16x8*)&As[(wm * 64 + i * 16 + r16) * 32 + q * 8];
    #pragma unroll
    for (int j = 0; j < 4; ++j)
      bfv[j] = *(const bf16x8*)&Bs[(wn * 64 + j * 16 + r16) * 32 + q * 8];
    #pragma unroll
    for (int i = 0; i < 4; ++i)
      #pragma unroll
      for (int j = 0; j < 4; ++j)
        acc[i][j] = __builtin_amdgcn_mfma_f32_16x16x32_bf16(af[i], bfv[j], acc[i][j], 0, 0, 0);
    __syncthreads();
  }
  #pragma unroll
  for (int j = 0; j < 4; ++j) {
    int col = n0 + wn * 64 + j * 16 + r16;
    float bv = bias[(size_t)e * RH + col];
    #pragma unroll
    for (int i = 0; i < 4; ++i) {
      int row = row0 + wm * 64 + i * 16 + q * 4;
      #pragma unroll
      for (int t2 = 0; t2 < 4; ++t2)
        C[(size_t)(row + t2) * RH + col] = f2bf(gelu_f(acc[i][j][t2] + bv));
    }
  }
}

// ---- grouped expert GEMM2: F1g [slot][HE] @ We2[e]^T -> pairout [slot][DD] (no bias) ----
__global__ __launch_bounds__(256)
void k_gemm_g2(const unsigned short* __restrict__ A, const unsigned short* __restrict__ W,
               unsigned short* __restrict__ C, const int* __restrict__ tile_e,
               const int* __restrict__ tile_r0, const int* __restrict__ ntiles) {
  if ((int)blockIdx.y >= *ntiles) return;
  __shared__ __align__(16) unsigned short As[128 * 32];
  __shared__ __align__(16) unsigned short Bs[128 * 32];
  const int tid = threadIdx.x;
  const int w = tid >> 6, lane = tid & 63;
  const int q = lane >> 4, r16 = lane & 15;
  const int e = tile_e[blockIdx.y];
  const int row0 = tile_r0[blockIdx.y];
  const int n0 = blockIdx.x * 128;
  f32x4 acc[4][4];
  #pragma unroll
  for (int i = 0; i < 4; ++i)
    #pragma unroll
    for (int j = 0; j < 4; ++j) acc[i][j] = (f32x4){0.f, 0.f, 0.f, 0.f};
  const int srow = w * 32 + (lane >> 2);
  const int scol = (lane & 3) * 8;
  const unsigned short* a_src = A + (size_t)(row0 + srow) * HE + scol;
  const unsigned short* b_src = W + (size_t)e * DD * HE + (size_t)(n0 + srow) * HE + scol;
  unsigned short* a_dst = &As[w * 1024];
  unsigned short* b_dst = &Bs[w * 1024];
  const int wm = w >> 1, wn = w & 1;
  for (int kt = 0; kt < HE; kt += 32) {
    GLD(a_src + kt, a_dst);
    GLD(a_src + kt + (size_t)16 * HE, a_dst + 512);
    GLD(b_src + kt, b_dst);
    GLD(b_src + kt + (size_t)16 * HE, b_dst + 512);
    __syncthreads();
    bf16x8 af[4], bfv[4];
    #pragma unroll
    for (int i = 0; i < 4; ++i)
      af[i] = *(const bf16x8*)&As[(wm * 64 + i * 16 + r16) * 32 + q * 8];
    #pragma unroll
    for (int j = 0; j < 4; ++j)
      bfv[j] = *(const bf16x8*)&Bs[(wn * 64 + j * 16 + r16) * 32 + q * 8];
    #pragma unroll
    for (int i = 0; i < 4; ++i)
      #pragma unroll
      for (int j = 0; j < 4; ++j)
        acc[i][j] = __builtin_amdgcn_mfma_f32_16x16x32_bf16(af[i], bfv[j], acc[i][j], 0, 0, 0);
    __syncthreads();
  }
  #pragma unroll
  for (int j = 0; j < 4; ++j) {
    int col = n0 + wn * 64 + j * 16 + r16;
    #pragma unroll
    for (int i = 0; i < 4; ++i) {
      int row = row0 + wm * 64 + i * 16 + q * 4;
      #pragma unroll
      for (int t2 = 0; t2 < 4; ++t2)
        C[(size_t)(row + t2) * DD + col] = f2bf(acc[i][j][t2]);
    }
  }
}

// ---- split-precision router GEMM1: (Ah+Al) @ (Bh+Bl)^T, 3 MFMA per tile, gelu, fp32 out ----
__global__ __launch_bounds__(256)
void k_gemm_split(const unsigned short* __restrict__ Ah, const unsigned short* __restrict__ Al,
                  const unsigned short* __restrict__ Bh, const unsigned short* __restrict__ Bl,
                  const float* __restrict__ bias, float* __restrict__ C, int N, int K) {
  __shared__ __align__(16) unsigned short Ahs[128 * 32];
  __shared__ __align__(16) unsigned short Als[128 * 32];
  __shared__ __align__(16) unsigned short Bhs[128 * 32];
  __shared__ __align__(16) unsigned short Bls[128 * 32];
  const int tid = threadIdx.x;
  const int w = tid >> 6, lane = tid & 63;
  const int q = lane >> 4, r16 = lane & 15;
  const int n0 = blockIdx.x * 128, m0 = blockIdx.y * 128;
  f32x4 acc[4][4];
  #pragma unroll
  for (int i = 0; i < 4; ++i)
    #pragma unroll
    for (int j = 0; j < 4; ++j) acc[i][j] = (f32x4){0.f, 0.f, 0.f, 0.f};
  const int srow = w * 32 + (lane >> 2);
  const int scol = (lane & 3) * 8;
  const unsigned short* ah_src = Ah + (size_t)(m0 + srow) * K + scol;
  const unsigned short* al_src = Al + (size_t)(m0 + srow) * K + scol;
  const unsigned short* bh_src = Bh + (size_t)(n0 + srow) * K + scol;
  const unsigned short* bl_src = Bl + (size_t)(n0 + srow) * K + scol;
  const int wm = w >> 1, wn = w & 1;
  for (int kt = 0; kt < K; kt += 32) {
    GLD(ah_src + kt, &Ahs[w * 1024]);
    GLD(ah_src + kt + (size_t)16 * K, &Ahs[w * 1024 + 512]);
    GLD(al_src + kt, &Als[w * 1024]);
    GLD(al_src + kt + (size_t)16 * K, &Als[w * 1024 + 512]);
    GLD(bh_src + kt, &Bhs[w * 1024]);
    GLD(bh_src + kt + (size_t)16 * K, &Bhs[w * 1024 + 512]);
    GLD(bl_src + kt, &Bls[w * 1024]);
    GLD(bl_src + kt + (size_t)16 * K, &Bls[w * 1024 + 512]);
    __syncthreads();
    bf16x8 ah[4], al[4], bh[4], bl[4];
    #pragma unroll
    for (int i = 0; i < 4; ++i) {
      int o = (wm * 64 + i * 16 + r16) * 32 + q * 8;
      ah[i] = *(const bf16x8*)&Ahs[o];
      al[i] = *(const bf16x8*)&Als[o];
    }
    #pragma unroll
    for (int j = 0; j < 4; ++j) {
      int o = (wn * 64 + j * 16 + r16) * 32 + q * 8;
      bh[j] = *(const bf16x8*)&Bhs[o];
      bl[j] = *(const bf16x8*)&Bls[o];
    }
    #pragma unroll
    for (int i = 0; i < 4; ++i)
      #pragma unroll
      for (int j = 0; j < 4; ++j) {
        acc[i][j] = __builtin_amdgcn_mfma_f32_16x16x32_bf16(ah[i], bh[j], acc[i][j], 0, 0, 0);
        acc[i][j] = __builtin_amdgcn_mfma_f32_16x16x32_bf16(al[i], bh[j], acc[i][j], 0, 0, 0);
        acc[i][j] = __builtin_amdgcn_mfma_f32_16x16x32_bf16(ah[i], bl[j], acc[i][j], 0, 0, 0);
      }
    __syncthreads();
  }
  #pragma unroll
  for (int j = 0; j < 4; ++j) {
    int col = n0 + wn * 64 + j * 16 + r16;
    float bv = bias[col];
    #pragma unroll
    for (int i = 0; i < 4; ++i) {
      int row = m0 + wm * 64 + i * 16 + q * 4;
      #pragma unroll
      for (int t2 = 0; t2 < 4; ++t2)
        C[(size_t)(row + t2) * N + col] = gelu_f(acc[i][j][t2] + bv);
    }
  }
}

// ---- router GEMM2 + softmax + top2 -> sel; flag near-tie tokens (+zero their logit slot) ----
__global__ void k_logits(const float* __restrict__ r, const float* __restrict__ w2,
                         const float* __restrict__ b2, const float* __restrict__ temp,
                         int* __restrict__ sel_i, float* __restrict__ sel_p,
                         int* __restrict__ flag, float* __restrict__ lg32) {
  int t = blockIdx.x, tid = threadIdx.x;
  const float* rr = r + (size_t)t * RH;
  float acc[NE];
  #pragma unroll
  for (int e = 0; e < NE; ++e) acc[e] = 0.f;
  #pragma unroll
  for (int k4 = 0; k4 < 4; ++k4) {
    float4 rv4 = ((const float4*)rr)[tid * 4 + k4];
    #pragma unroll
    for (int kk = 0; kk < 4; ++kk) {
      int d = tid * 16 + k4 * 4 + kk;
      float rv = (kk == 0) ? rv4.x : (kk == 1) ? rv4.y : (kk == 2) ? rv4.z : rv4.w;
      const float4* wr = (const float4*)(w2 + (size_t)d * NE);
      float4 w0 = wr[0], w1 = wr[1];
      acc[0] += rv * w0.x; acc[1] += rv * w0.y; acc[2] += rv * w0.z; acc[3] += rv * w0.w;
      acc[4] += rv * w1.x; acc[5] += rv * w1.y; acc[6] += rv * w1.z; acc[7] += rv * w1.w;
    }
  }
  #pragma unroll
  for (int off = 32; off > 0; off >>= 1)
    #pragma unroll
    for (int e = 0; e < NE; ++e) acc[e] += __shfl_down(acc[e], off);
  __shared__ float shl[4][NE];
  int w = tid >> 6, lane = tid & 63;
  if (lane == 0) {
    #pragma unroll
    for (int e = 0; e < NE; ++e) shl[w][e] = acc[e];
  }
  __syncthreads();
  if (tid == 0) {
    float tmp = temp[0];
    float lg[NE];
    #pragma unroll
    for (int e = 0; e < NE; ++e)
      lg[e] = (shl[0][e] + shl[1][e] + shl[2][e] + shl[3][e] + b2[e]) / tmp;
    float mx = lg[0];
    for (int e = 1; e < NE; ++e) mx = fmaxf(mx, lg[e]);
    float p[NE], se = 0.f;
    for (int e = 0; e < NE; ++e) { p[e] = expf(lg[e] - mx); se += p[e]; }
    float inv = 1.f / se;
    int i1 = 0; float p1 = p[0];
    for (int e = 1; e < NE; ++e) if (p[e] > p1) { p1 = p[e]; i1 = e; }
    int i2 = -1; float p2 = -1.f;
    for (int e = 0; e < NE; ++e) if (e != i1 && p[e] > p2) { p2 = p[e]; i2 = e; }
    sel_i[t * 2] = i1; sel_i[t * 2 + 1] = i2;
    sel_p[t * 2] = p1 * inv; sel_p[t * 2 + 1] = p2 * inv;
    // flag if 2nd/3rd logit gap is within split-precision noise margin
    float a1 = -1e30f, a2 = -1e30f, a3 = -1e30f;
    for (int e = 0; e < NE; ++e) {
      float vv = lg[e];
      if (vv > a1) { a3 = a2; a2 = a1; a1 = vv; }
      else if (vv > a2) { a3 = a2; a2 = vv; }
      else if (vv > a3) a3 = vv;
    }
    int fl = (a2 - a3 < 0.01f) ? 1 : 0;
    flag[t] = fl;
    if (fl) {
      #pragma unroll
      for (int e = 0; e < NE; ++e) lg32[(size_t)t * NE + e] = 0.f;
    }
  }
}

// ---- parallel exact fp32 recompute of raw logits for flagged tokens ----
__global__ void k_triage2(const int* __restrict__ flag, const float* __restrict__ xh32,
                          const float* __restrict__ W32, const float* __restrict__ biasr,
                          const float* __restrict__ w2, float* __restrict__ lg32) {
  int t = blockIdx.y;
  if (flag[t] == 0) return;
  int tid = threadIdx.x;
  int w = tid >> 6, lane = tid & 63;
  __shared__ float xs[DD];
  ((float4*)xs)[tid] = ((const float4*)(xh32 + (size_t)t * DD))[tid];
  __syncthreads();
  int hh0 = blockIdx.x * 64 + w * 16;
  float acc[NE];
  #pragma unroll
  for (int e = 0; e < NE; ++e) acc[e] = 0.f;
  #pragma unroll
  for (int r = 0; r < 16; ++r) {
    int hh = hh0 + r;
    const float4* wrow = (const float4*)(W32 + (size_t)hh * DD);
    float s = 0.f;
    #pragma unroll
    for (int c = 0; c < 4; ++c) {
      float4 wv = wrow[lane + 64 * c];
      float4 xv = ((const float4*)xs)[lane + 64 * c];
      s += wv.x * xv.x + wv.y * xv.y + wv.z * xv.z + wv.w * xv.w;
    }
    #pragma unroll
    for (int off = 32; off > 0; off >>= 1) s += __shfl_down(s, off);
    if (lane == 0) {
      float r1 = gelu_f(s + biasr[hh]);
      const float* wr = w2 + (size_t)hh * NE;
      #pragma unroll
      for (int e = 0; e < NE; ++e) acc[e] += r1 * wr[e];
    }
  }
  __shared__ float sh2[4][NE];
  if (lane == 0) {
    #pragma unroll
    for (int e = 0; e < NE; ++e) sh2[w][e] = acc[e];
  }
  __syncthreads();
  if (tid < NE) {
    float v = sh2[0][tid] + sh2[1][tid] + sh2[2][tid] + sh2[3][tid];
    atomicAdd(&lg32[(size_t)t * NE + tid], v);
  }
}

// ---- finalize sel for flagged tokens from exact logits ----
__global__ void k_gate2(const int* __restrict__ flag, const float* __restrict__ lg32,
                        const float* __restrict__ b2, const float* __restrict__ temp,
                        int* __restrict__ sel_i, float* __restrict__ sel_p) {
  int t = blockIdx.x * 256 + threadIdx.x;
  if (t >= TOK || flag[t] == 0) return;
  float tmp = temp[0];
  float lg[NE];
  #pragma unroll
  for (int e = 0; e < NE; ++e) lg[e] = (lg32[(size_t)t * NE + e] + b2[e]) / tmp;
  float mx = lg[0];
  for (int e = 1; e < NE; ++e) mx = fmaxf(mx, lg[e]);
  float p[NE], se = 0.f;
  for (int e = 0; e < NE; ++e) { p[e] = expf(lg[e] - mx); se += p[e]; }
  float inv = 1.f / se;
  int i1 = 0; float p1 = p[0];
  for (int e = 1; e < NE; ++e) if (p[e] > p1) { p1 = p[e]; i1 = e; }
  int i2 = -1; float p2 = -1.f;
  for (int e = 0; e < NE; ++e) if (e != i1 && p[e] > p2) { p2 = p[e]; i2 = e; }
  sel_i[t * 2] = i1; sel_i[t * 2 + 1] = i2;
  sel_p[t * 2] = p1 * inv; sel_p[t * 2 + 1] = p2 * inv;
}

// ---- expert bucketing (device-side, graph-capture safe) ----
__global__ void k_count(const int* __restrict__ sel_i, int* __restrict__ cnt) {
  int t = blockIdx.x * 256 + threadIdx.x;
  if (t >= TOK) return;
  atomicAdd(&cnt[sel_i[2 * t]], 1);
  atomicAdd(&cnt[sel_i[2 * t + 1]], 1);
}

__global__ void k_offsets(const int* __restrict__ cnt, int* __restrict__ off,
                          int* __restrict__ tile_e, int* __restrict__ tile_r0,
                          int* __restrict__ ntiles) {
  if (threadIdx.x == 0) {
    int cur = 0, nt = 0;
    for (int e = 0; e < NE; ++e) {
      off[e] = cur;
      int n = (cnt[e] + 127) >> 7;
      for (int k = 0; k < n; ++k) { tile_e[nt] = e; tile_r0[nt] = cur + 128 * k; nt++; }
      cur += n * 128;
    }
    *ntiles = nt;
  }
}

__global__ void k_fill(const int* __restrict__ sel_i, const int* __restrict__ off,
                       int* __restrict__ fill, int* __restrict__ slotarr,
                       int* __restrict__ tok_of) {
  int t = blockIdx.x * 256 + threadIdx.x;
  if (t >= TOK) return;
  #pragma unroll
  for (int j = 0; j < 2; ++j) {
    int e = sel_i[2 * t + j];
    int pos = atomicAdd(&fill[e], 1);
    int s = off[e] + pos;
    slotarr[2 * t + j] = s;
    tok_of[s] = t;
  }
}

// ---- combined = w0*(pairout[s0]+b2[e0]) + w1*(pairout[s1]+b2[e1]); LN -> xc ----
__global__ void k_combine2(const int* __restrict__ slotarr, const int* __restrict__ sel_i,
                           const float* __restrict__ sel_p, const unsigned short* __restrict__ pairout,
                           const float* __restrict__ e_b2, unsigned short* __restrict__ xc) {
  int t = blockIdx.x, tid = threadIdx.x;
  int s0 = slotarr[t * 2], s1 = slotarr[t * 2 + 1];
  int e0 = sel_i[t * 2], e1 = sel_i[t * 2 + 1];
  float w0 = sel_p[t * 2], w1 = sel_p[t * 2 + 1];
  ushort4 u0 = ((const ushort4*)(pairout + (size_t)s0 * DD))[tid];
  ushort4 u1 = ((const ushort4*)(pairout + (size_t)s1 * DD))[tid];
  float4 b0 = ((const float4*)(e_b2 + (size_t)e0 * DD))[tid];
  float4 b1v = ((const float4*)(e_b2 + (size_t)e1 * DD))[tid];
  float v[4];
  v[0] = w0 * (bf2f(u0.x) + b0.x) + w1 * (bf2f(u1.x) + b1v.x);
  v[1] = w0 * (bf2f(u0.y) + b0.y) + w1 * (bf2f(u1.y) + b1v.y);
  v[2] = w0 * (bf2f(u0.z) + b0.z) + w1 * (bf2f(u1.z) + b1v.z);
  v[3] = w0 * (bf2f(u0.w) + b0.w) + w1 * (bf2f(u1.w) + b1v.w);
  float s1f = v[0] + v[1] + v[2] + v[3];
  float s2f = v[0]*v[0] + v[1]*v[1] + v[2]*v[2] + v[3]*v[3];
  float mean, rstd;
  block_ln_stats(s1f, s2f, mean, rstd);
  ushort4 o;
  o.x = f2bf((v[0] - mean) * rstd); o.y = f2bf((v[1] - mean) * rstd);
  o.z = f2bf((v[2] - mean) * rstd); o.w = f2bf((v[3] - mean) * rstd);
  ((ushort4*)(xc + (size_t)t * DD))[tid] = o;
}

// ---- out = layernorm(h + c2, o_g, o_b) ----
__global__ void k_final(const float* __restrict__ h, const unsigned short* __restrict__ c2,
                        const float* __restrict__ og, const float* __restrict__ ob,
                        float* __restrict__ out) {
  int t = blockIdx.x, tid = threadIdx.x;
  float4 hv = ((const float4*)(h + (size_t)t * DD))[tid];
  ushort4 cu = ((const ushort4*)(c2 + (size_t)t * DD))[tid];
  float v[4] = {hv.x + bf2f(cu.x), hv.y + bf2f(cu.y), hv.z + bf2f(cu.z), hv.w + bf2f(cu.w)};
  float s1 = v[0] + v[1] + v[2] + v[3];
  float s2 = v[0]*v[0] + v[1]*v[1] + v[2]*v[2] + v[3]*v[3];
  float mean, rstd;
  block_ln_stats(s1, s2, mean, rstd);
  float4 gv = ((const float4*)og)[tid];
  float4 bv = ((const float4*)ob)[tid];
  float4 o;
  o.x = (v[0] - mean) * rstd * gv.x + bv.x;
  o.y = (v[1] - mean) * rstd * gv.y + bv.y;
  o.z = (v[2] - mean) * rstd * gv.z + bv.z;
  o.w = (v[3] - mean) * rstd * gv.w + bv.w;
  ((float4*)(out + (size_t)t * DD))[tid] = o;
}

extern "C" void kernel_launch(void* const* d_in, const int* in_sizes, int n_in,
                              void* d_out, int out_size, void* d_ws, size_t ws_size,
                              hipStream_t stream) {
  (void)in_sizes; (void)n_in; (void)out_size; (void)ws_size;
  const float* x      = (const float*)d_in[0];
  const float* r_ln_g = (const float*)d_in[1];
  const float* r_ln_b = (const float*)d_in[2];
  const float* r_w1   = (const float*)d_in[3];
  const float* r_b1   = (const float*)d_in[4];
  const float* r_w2   = (const float*)d_in[5];
  const float* r_b2   = (const float*)d_in[6];
  const float* temp   = (const float*)d_in[7];
  const float* e_ln_g = (const float*)d_in[8];
  const float* e_ln_b = (const float*)d_in[9];
  const float* e_w1   = (const float*)d_in[10];
  const float* e_b1   = (const float*)d_in[11];
  const float* e_w2   = (const float*)d_in[12];
  const float* e_b2   = (const float*)d_in[13];
  const float* c_ln_g = (const float*)d_in[14];
  const float* c_ln_b = (const float*)d_in[15];
  const float* c_w1   = (const float*)d_in[16];
  const float* c_b1   = (const float*)d_in[17];
  const float* c_w2   = (const float*)d_in[18];
  const float* c_b2   = (const float*)d_in[19];
  const float* o_ln_g = (const float*)d_in[20];
  const float* o_ln_b = (const float*)d_in[21];
  float* out = (float*)d_out;

  char* base = (char*)d_ws;
  long long cur = 0;
  auto take = [&](long long sz) { char* r = base + cur; cur += (sz + 255) & ~255LL; return r; };

  float* h      = (float*)take(8388608);            // [2048,1024] fp32
  float* xh32   = (float*)take(8388608);            // xhat fp32
  unsigned short* xhi = (unsigned short*)take(4194304); // xhat bf16 hi
  unsigned short* xlo = (unsigned short*)take(4194304); // xhat bf16 lo
  unsigned short* WrH = (unsigned short*)take(8388608); // router W1^T*g hi
  unsigned short* WrL = (unsigned short*)take(8388608);
  float* Wr32   = (float*)take(16777216);           // router W1^T*g fp32 (triage)
  float* biasr  = (float*)take(16384);
  float* ract   = (float*)take(33554432);           // gelu(router GEMM1) fp32
  int*   flag   = (int*)take(8192);
  float* lg32   = (float*)take(65536);              // exact fp32 logits (triage accum)
  int*   sel_i  = (int*)take(16384);                // [TOK][2] expert idx
  float* sel_p  = (float*)take(16384);              // [TOK][2] gate prob
  int*   cnt    = (int*)take(256);
  int*   off    = (int*)take(256);
  int*   fillc  = (int*)take(256);
  int*   tile_e = (int*)take(256);
  int*   tile_r0= (int*)take(256);
  int*   ntiles = (int*)take(256);
  int*   slotarr= (int*)take(16384);                // [TOK][2] -> pair slot
  int*   tok_of = (int*)take(MAXROWS * 4);          // pair slot -> token
  unsigned short* We1 = (unsigned short*)take(67108864); // [8][4096,1024]
  float* be1    = (float*)take(131072);
  unsigned short* We2 = (unsigned short*)take(67108864); // [8][1024,4096]
  unsigned short* Wc1 = (unsigned short*)take(4194304);
  float* bc1    = (float*)take(8192);
  unsigned short* Wc2 = (unsigned short*)take(4194304);
  unsigned short* xc  = (unsigned short*)take(4194304);
  unsigned short* c1  = (unsigned short*)take(8388608);
  unsigned short* c2  = (unsigned short*)take(4194304);
  unsigned short* F1g = (unsigned short*)take((long long)MAXROWS * RH * 2);  // 40 MB
  unsigned short* pairout = (unsigned short*)take((long long)MAXROWS * DD * 2); // 10 MB

  // zero bucketing state (ws is poisoned each call)
  hipMemsetAsync(cnt, 0, 256, stream);
  hipMemsetAsync(fillc, 0, 256, stream);
  hipMemsetAsync(tok_of, 0, MAXROWS * 4, stream);

  // prep + weight conversion
  k_prep<<<TOK, 256, 0, stream>>>(x, h, xh32, xhi, xlo);
  k_tconv_split<<<dim3(RH/32, DD/32, 1), 256, 0, stream>>>(r_w1, r_ln_g, WrH, WrL, Wr32, DD, RH);
  k_tconv<<<dim3(RH/32, DD/32, NE), 256, 0, stream>>>(e_w1, e_ln_g, We1, DD, RH,
      (long long)DD*RH, (long long)DD, (long long)RH*DD);
  k_tconv<<<dim3(DD/32, HE/32, NE), 256, 0, stream>>>(e_w2, nullptr, We2, HE, DD,
      (long long)HE*DD, 0LL, (long long)DD*HE);
  k_tconv<<<dim3(CH/32, DD/32, 1), 256, 0, stream>>>(c_w1, c_ln_g, Wc1, DD, CH, 0LL, 0LL, 0LL);
  k_tconv<<<dim3(DD/32, CH/32, 1), 256, 0, stream>>>(c_w2, nullptr, Wc2, CH, DD, 0LL, 0LL, 0LL);
  k_foldbias<<<dim3(RH/256, 1), 256, 0, stream>>>(r_w1, r_ln_b, r_b1, biasr, DD, RH, 0LL, 0LL, 0LL, 0LL);
  k_foldbias<<<dim3(RH/256, NE), 256, 0, stream>>>(e_w1, e_ln_b, e_b1, be1, DD, RH,
      (long long)DD*RH, (long long)DD, (long long)RH, (long long)RH);
  k_foldbias<<<dim3(CH/256, 1), 256, 0, stream>>>(c_w1, c_ln_b, c_b1, bc1, DD, CH, 0LL, 0LL, 0LL, 0LL);

  // router (split precision) + top2 + near-tie parallel triage
  k_gemm_split<<<dim3(RH/128, TOK/128, 1), 256, 0, stream>>>(xhi, xlo, WrH, WrL, biasr, ract, RH, DD);
  k_logits<<<TOK, 256, 0, stream>>>(ract, r_w2, r_b2, temp, sel_i, sel_p, flag, lg32);
  k_triage2<<<dim3(RH/64, TOK), 256, 0, stream>>>(flag, xh32, Wr32, biasr, r_w2, lg32);
  k_gate2<<<TOK/256, 256, 0, stream>>>(flag, lg32, r_b2, temp, sel_i, sel_p);

  // bucket (token,expert) pairs by expert
  k_count<<<TOK/256, 256, 0, stream>>>(sel_i, cnt);
  k_offsets<<<1, 64, 0, stream>>>(cnt, off, tile_e, tile_r0, ntiles);
  k_fill<<<TOK/256, 256, 0, stream>>>(sel_i, off, fillc, slotarr, tok_of);

  // sparse grouped expert FFN (only selected pairs)
  k_gemm_g1<<<dim3(RH/128, MAXTILE), 256, 0, stream>>>(xhi, We1, be1, F1g,
      tok_of, tile_e, tile_r0, ntiles);
  k_gemm_g2<<<dim3(DD/128, MAXTILE), 256, 0, stream>>>(F1g, We2, pairout,
      tile_e, tile_r0, ntiles);

  // combine + combiner MLP + residual/output LN
  k_combine2<<<TOK, 256, 0, stream>>>(slotarr, sel_i, sel_p, pairout, e_b2, xc);
  k_gemm<1,1><<<dim3(CH/128, TOK/128, 1), 256, 0, stream>>>(xc, Wc1, bc1, (void*)c1, CH, DD, 0LL, 0LL, 0LL, 0LL);
  k_gemm<0,1><<<dim3(DD/128, TOK/128, 1), 256, 0, stream>>>(c1, Wc2, c_b2, (void*)c2, DD, CH, 0LL, 0LL, 0LL, 0LL);
  k_final<<<TOK, 256, 0, stream>>>(h, c2, o_ln_g, o_ln_b, out);
}